// Round 2
// baseline (515.795 us; speedup 1.0000x reference)
//
#include <hip/hip_runtime.h>
#include <cstdint>

#define B_ 16
#define L_ 512
#define N_ 8192
#define K_ 30
#define E_ (N_*K_)
#define H_ 32
#define C_ 35

typedef uint16_t u16;
typedef uint32_t u32;
typedef unsigned long long u64;
typedef float f2v __attribute__((ext_vector_type(2)));

static __device__ __forceinline__ f2v splat2(float x) { f2v v; v.x = x; v.y = x; return v; }

// adaptive float load: bf16 (u16<<16) or fp32
static __device__ __forceinline__ float ldf(const void* p, int i, int bf) {
    return bf ? __uint_as_float(((u32)((const u16*)p)[i]) << 16)
              : ((const float*)p)[i];
}
static __device__ __forceinline__ float bfu16(u16 x) {
    return __uint_as_float(((u32)x) << 16);
}
// mask load: mode 0 = u8 bool, 1 = int32, 2 = int64 (little-endian low word)
static __device__ __forceinline__ int ldmask(const void* p, int i, int mode) {
    if (mode == 0) return ((const unsigned char*)p)[i] != 0;
    if (mode == 2) return ((const u32*)p)[2*i] != 0;
    return ((const u32*)p)[i] != 0;
}
// f32 -> bf16 RNE
static __device__ __forceinline__ u16 f2bf(float f) {
    u32 x = __float_as_uint(f);
    u32 r = x + 0x7FFFu + ((x >> 16) & 1u);
    return (u16)(r >> 16);
}
// fast silu (~1e-7 rel err)
static __device__ __forceinline__ float fsilu(float x) {
    return x * __builtin_amdgcn_rcpf(1.f + __expf(-x));
}
// wave-uniform-index register broadcast
static __device__ __forceinline__ float RL(float x, int i) {
    return __uint_as_float((u32)__builtin_amdgcn_readlane((int)__float_as_uint(x), i));
}

// wave-level dtype detection (deterministic)
static __device__ __forceinline__ int detect_bf(const void* tr, int lane) {
    const u16* p = (const u16*)tr;
    int cnt = 0;
    for (int i = lane; i < 256; i += 64) {
        u16 v = p[2 * i];
        int e = (v >> 7) & 0xFF;
        if ((e >= 100 && e <= 141) || (v & 0x7FFFu) == 0) cnt++;
    }
    #pragma unroll
    for (int d = 1; d < 64; d <<= 1) cnt += __shfl_xor(cnt, d, 64);
    return cnt >= 192;
}
static __device__ __forceinline__ int detect_mm(const void* xmv, int lane) {
    const u32* xm = (const u32*)xmv;
    int anyBig = 0, oddNZ = 0;
    for (int i = lane; i < 1024; i += 64) {
        u32 w = xm[i];
        if (w & ~1u) anyBig = 1;
        if ((i & 1) && w) oddNZ = 1;
    }
    #pragma unroll
    for (int d = 1; d < 64; d <<= 1) {
        anyBig |= __shfl_xor(anyBig, d, 64);
        oddNZ  |= __shfl_xor(oddNZ, d, 64);
    }
    return anyBig ? 0 : (oddNZ ? 1 : 2);
}

__constant__ float cBB[9] = {-0.525f, 1.363f, 0.f,  0.f, 0.f, 0.f,  1.526f, 0.f, 0.f};

// u32 DPP min step (VALU pipe; d2>=0 -> f32 bit order == u32 order)
#define DPP_UMIN(var, CTRL) \
    { u32 o_ = (u32)__builtin_amdgcn_update_dpp((int)(var), (int)(var), CTRL, 0xF, 0xF, false); \
      (var) = (o_ < (var)) ? o_ : (var); }
#define DPP_UMIN_ALL(var) \
    DPP_UMIN(var, 0x111) DPP_UMIN(var, 0x112) DPP_UMIN(var, 0x114) \
    DPP_UMIN(var, 0x118) DPP_UMIN(var, 0x142) DPP_UMIN(var, 0x143)

// f32 add-reduce over 8-lane group via DPP (bit-identical to shfl_xor 1/2/4 tree)
#define DPP_ADD8(part) \
    part += __uint_as_float((u32)__builtin_amdgcn_update_dpp( \
        (int)__float_as_uint(part), (int)__float_as_uint(part), 0xB1, 0xF, 0xF, false)); \
    part += __uint_as_float((u32)__builtin_amdgcn_update_dpp( \
        (int)__float_as_uint(part), (int)__float_as_uint(part), 0x4E, 0xF, 0xF, false)); \
    part += __uint_as_float((u32)__builtin_amdgcn_update_dpp( \
        (int)__float_as_uint(part), (int)__float_as_uint(part), 0x141, 0xF, 0xF, false));

// packed f32 FMA with op_sel scalar broadcast from one half of rr (bitwise == scalar fma)
#define PKFMA_LO(acc, rr, w) \
    asm("v_pk_fma_f32 %0, %1, %2, %0 op_sel:[0,0,0] op_sel_hi:[0,1,1]" \
        : "+v"(acc) : "v"(rr), "v"(w))
#define PKFMA_HI(acc, rr, w) \
    asm("v_pk_fma_f32 %0, %1, %2, %0 op_sel:[1,0,0] op_sel_hi:[1,1,1]" \
        : "+v"(acc) : "v"(rr), "v"(w))

// =============== kernel A: fused kNN + prep, grid exactly 2048 (fully CU-resident) =========
// blocks [0,1024)    : kNN, 8 targets/block (wave wid -> targets t0+wid, t0+wid+4)
//                      + weight-convert slice (7 elems/block on tid<7)
// blocks [1024,2048) : prep, 8 nodes/block (wave wid -> nodes nb+wid, nb+wid+4)
//                      + one ptab row (row = bid-1024, cols on tid<128)
__global__ __launch_bounds__(256, 8) void knn_prep_kernel(
    const void* __restrict__ rots, const void* __restrict__ trans,
    const void* __restrict__ node,
    const void* __restrict__ xm, const void* __restrict__ nm,
    const void* __restrict__ Wa, const void* __restrict__ av,
    const void* __restrict__ Wv, const void* __restrict__ Wo,
    const void* __restrict__ Wg, const void* __restrict__ W2,
    int* __restrict__ flag, int* __restrict__ srcArr,
    float* __restrict__ hsrc, float* __restrict__ htgt,
    float* __restrict__ ptab, float* __restrict__ V,
    float* __restrict__ c_wrb, float* __restrict__ c_av,
    float* __restrict__ c_Wo, float* __restrict__ c_Wg, float* __restrict__ c_W2)
{
    __shared__ float sX[L_], sY[L_], sZ[L_];
    __shared__ int flagS[2];
    const int bid = blockIdx.x, tid = threadIdx.x;
    const int lane = tid & 63, wid = tid >> 6;

    if (wid == 0) {
        int bfv = detect_bf(trans, lane);
        int mmv = 0;
        if (bid >= 1024) mmv = detect_mm(xm, lane);
        if (bid == 0 && lane == 0) flag[0] = bfv;   // for kernel B
        if (lane == 0) { flagS[0] = bfv; flagS[1] = mmv; }
    }
    __syncthreads();
    const int bf = flagS[0];

    if (bid < 1024) {
        // ---------------- kNN: 8 targets, 2 per wave ----------------
        const int t0 = bid * 8;
        const int base = t0 & ~511;
        if (bf) {
            const u16* tp = (const u16*)trans;
            for (int i = tid; i < L_; i += 256) {
                sX[i] = bfu16(tp[(base + i) * 3 + 0]);
                sY[i] = bfu16(tp[(base + i) * 3 + 1]);
                sZ[i] = bfu16(tp[(base + i) * 3 + 2]);
            }
        } else {
            const float* tp = (const float*)trans;
            for (int i = tid; i < L_; i += 256) {
                sX[i] = tp[(base + i) * 3 + 0];
                sY[i] = tp[(base + i) * 3 + 1];
                sZ[i] = tp[(base + i) * 3 + 2];
            }
        }
        __syncthreads();

        for (int ti = 0; ti < 2; ++ti) {
            const int t = t0 + wid + (ti << 2);
            const int l = t & 511;
            const float tx = sX[l], ty = sY[l], tz = sZ[l];

            u32 d2b[8];
            #pragma unroll
            for (int i = 0; i < 8; ++i) {
                int j = lane + (i << 6);
                float dx = __fsub_rn(tx, sX[j]);
                float dy = __fsub_rn(ty, sY[j]);
                float dz = __fsub_rn(tz, sZ[j]);
                float d2 = __fadd_rn(__fadd_rn(__fmul_rn(dx, dx), __fmul_rn(dy, dy)), __fmul_rn(dz, dz));
                if (j == l) d2 = __fadd_rn(d2, 1e9f);
                d2b[i] = __float_as_uint(d2);
            }

            int myres = 0;
            for (int k = 0; k < K_; ++k) {
                u32 bb = d2b[0]; int bs = 0;
                #pragma unroll
                for (int i = 1; i < 8; ++i)
                    if (d2b[i] < bb) { bb = d2b[i]; bs = i; }
                u32 m = bb;
                DPP_UMIN_ALL(m)
                u32 gbits = (u32)__builtin_amdgcn_readlane((int)m, 63);
                u64 mask = __ballot(bb == gbits);
                u32 gidx;
                if (__popcll(mask) == 1) {
                    int wl = __ffsll((long long)mask) - 1;
                    gidx = (u32)__builtin_amdgcn_readlane((int)((bs << 6) | lane), wl);
                } else {
                    u32 cand = (bb == gbits) ? (u32)((bs << 6) | lane) : 0xFFFFFFFFu;
                    DPP_UMIN_ALL(cand)
                    gidx = (u32)__builtin_amdgcn_readlane((int)cand, 63);
                }
                if (lane == (u32)k) myres = (int)(gidx & 511u);
                if ((gidx & 63u) == (u32)lane) {
                    int ws = (int)(gidx >> 6);
                    #pragma unroll
                    for (int i = 0; i < 8; ++i)
                        if (ws == i) d2b[i] = 0xFFFFFFFFu;
                }
            }
            if (lane < K_) srcArr[t * K_ + lane] = base + myres;
        }

        // weight-convert slice: 7 elems per block covers 6272 over 1024 blocks
        if (tid < 7) {
            int i = bid * 7 + tid;
            if (i < 6272) {
                if      (i < 2048) c_wrb[i]        = ldf(Wa, 70 * 128 + i, bf);
                else if (i < 2176) c_av[i - 2048]  = ldf(av, i - 2048, bf);
                else if (i < 4224) c_Wo[i - 2176]  = ldf(Wo, i - 2176, bf);
                else if (i < 5248) c_Wg[i - 4224]  = ldf(Wg, i - 4224, bf);
                else               c_W2[i - 5248]  = ldf(W2, i - 5248, bf);
            }
        }

    } else {
        // ---------------- prep: 8 nodes, 2 per wave ----------------
        const int mm = flagS[1];
        const int nb = (bid - 1024) * 8;

        for (int ni = 0; ni < 2; ++ni) {
            const int n = nb + wid + (ni << 2);

            float eA, eB, eC = 0.f;
            {
                int s = lane;                       // 0..63
                int r = s / 35, c = s - r * 35;
                if (c < H_)      eA = ldf(node, n * 128 + r * 32 + c, bf);
                else if (r == 0) eA = (c == 34) ? ((ldmask(nm, n, mm) && !ldmask(xm, n, mm)) ? 1.f : 0.f) : 0.f;
                else {
                    int i = r - 1, a = c - 32;
                    eA = ldf(rots, n*9 + i*3 + 0, bf) * cBB[a*3 + 0]
                       + ldf(rots, n*9 + i*3 + 1, bf) * cBB[a*3 + 1]
                       + ldf(rots, n*9 + i*3 + 2, bf) * cBB[a*3 + 2];
                }
                s = lane + 64;                      // 64..127
                r = s / 35; c = s - r * 35;
                if (c < H_)      eB = ldf(node, n * 128 + r * 32 + c, bf);
                else {
                    int i = r - 1, a = c - 32;
                    eB = ldf(rots, n*9 + i*3 + 0, bf) * cBB[a*3 + 0]
                       + ldf(rots, n*9 + i*3 + 1, bf) * cBB[a*3 + 1]
                       + ldf(rots, n*9 + i*3 + 2, bf) * cBB[a*3 + 2];
                }
                if (lane < 12) {
                    s = lane + 128;                 // 128..139
                    r = s / 35; c = s - r * 35;
                    if (c < H_)      eC = ldf(node, n * 128 + r * 32 + c, bf);
                    else {
                        int i = r - 1, a = c - 32;
                        eC = ldf(rots, n*9 + i*3 + 0, bf) * cBB[a*3 + 0]
                           + ldf(rots, n*9 + i*3 + 1, bf) * cBB[a*3 + 1]
                           + ldf(rots, n*9 + i*3 + 2, bf) * cBB[a*3 + 2];
                    }
                }
            }

            float a0 = 0.f, a1 = 0.f, b0 = 0.f, b1 = 0.f;
            float v0 = 0.f, v1 = 0.f, v2 = 0.f, v3 = 0.f;
            if (bf) {
                const u16* wa = (const u16*)Wa;
                const u16* wv = (const u16*)Wv;
                #pragma unroll
                for (int i = 0; i < 35; ++i) {
                    float ei = RL(eA, i);
                    a0 = fmaf(ei, bfu16(wa[i * 128 + lane]),        a0);
                    a1 = fmaf(ei, bfu16(wa[i * 128 + lane + 64]),   a1);
                    b0 = fmaf(ei, bfu16(wa[(35 + i) * 128 + lane]),      b0);
                    b1 = fmaf(ei, bfu16(wa[(35 + i) * 128 + lane + 64]), b1);
                }
                #pragma unroll
                for (int cp = 0; cp < 35; ++cp) {
                    float w = bfu16(wv[cp * 64 + lane]);
                    float e1 = (35 + cp < 64) ? RL(eA, 35 + cp) : RL(eB, cp - 29);
                    float e3 = (cp < 23) ? RL(eB, 41 + cp) : RL(eC, cp - 23);
                    v0 = fmaf(RL(eA, cp), w, v0);
                    v1 = fmaf(e1, w, v1);
                    v2 = fmaf(RL(eB, cp + 6), w, v2);
                    v3 = fmaf(e3, w, v3);
                }
            } else {
                const float* wa = (const float*)Wa;
                const float* wv = (const float*)Wv;
                #pragma unroll
                for (int i = 0; i < 35; ++i) {
                    float ei = RL(eA, i);
                    a0 = fmaf(ei, wa[i * 128 + lane],        a0);
                    a1 = fmaf(ei, wa[i * 128 + lane + 64],   a1);
                    b0 = fmaf(ei, wa[(35 + i) * 128 + lane],      b0);
                    b1 = fmaf(ei, wa[(35 + i) * 128 + lane + 64], b1);
                }
                #pragma unroll
                for (int cp = 0; cp < 35; ++cp) {
                    float w = wv[cp * 64 + lane];
                    float e1 = (35 + cp < 64) ? RL(eA, 35 + cp) : RL(eB, cp - 29);
                    float e3 = (cp < 23) ? RL(eB, 41 + cp) : RL(eC, cp - 23);
                    v0 = fmaf(RL(eA, cp), w, v0);
                    v1 = fmaf(e1, w, v1);
                    v2 = fmaf(RL(eB, cp + 6), w, v2);
                    v3 = fmaf(e3, w, v3);
                }
            }
            hsrc[(size_t)n * 128 + lane]      = a0;
            hsrc[(size_t)n * 128 + lane + 64] = a1;
            htgt[(size_t)n * 128 + lane]      = b0;
            htgt[(size_t)n * 128 + lane + 64] = b1;
            float* vp = V + (size_t)n * 256 + lane;
            vp[0] = v0; vp[64] = v1; vp[128] = v2; vp[192] = v3;
        }

        // one ptab row per prep block: row d = bid-1024, cols tid<128
        const int d = bid - 1024;
        if (tid < 128) {
            float dd = (float)(d - 512);
            float acc = 0.f;
            if (bf) {
                const u16* wa = (const u16*)Wa;
                #pragma unroll
                for (int q = 0; q < 8; ++q) {
                    float fr = expf((float)(2 * q) * (-0.5756462732485115f)); // -ln(1e4)/16
                    float ang = dd * fr;
                    acc = fmaf(cosf(ang), bfu16(wa[(86 + q) * 128 + tid]), acc);
                    acc = fmaf(sinf(ang), bfu16(wa[(94 + q) * 128 + tid]), acc);
                }
            } else {
                const float* wa = (const float*)Wa;
                #pragma unroll
                for (int q = 0; q < 8; ++q) {
                    float fr = expf((float)(2 * q) * (-0.5756462732485115f));
                    float ang = dd * fr;
                    acc = fmaf(cosf(ang), wa[(86 + q) * 128 + tid], acc);
                    acc = fmaf(sinf(ang), wa[(94 + q) * 128 + tid], acc);
                }
            }
            ptab[(size_t)d * 128 + tid] = acc;
        }
    }
}

// =============== kernel B: wave-per-target, barrier-free, grid 2048 (fully resident) =======
// Wave wid of block bid owns target t = xcd-swizzled(bid)*4 + wid, end-to-end:
// edge meta -> rbf -> 30x logits GEMV -> wave-local softmax -> V-agg -> epilogue -> store.
// All LDS regions are wave-private ([wid]); no __syncthreads anywhere.
// Arithmetic sequence is bitwise-identical to the previous version.
__global__ __launch_bounds__(256, 8) void edge_agg_kernel(
    const void* __restrict__ trans, const int* __restrict__ srcArr,
    const float* __restrict__ hsrc, const float* __restrict__ htgt,
    const float* __restrict__ ptab, const float* __restrict__ V,
    const float* __restrict__ c_wrb, const float* __restrict__ c_av,
    const float* __restrict__ Wo, const float* __restrict__ Wg,
    const float* __restrict__ W2,
    const int* __restrict__ flag, void* __restrict__ outv)
{
    __shared__ __align__(16) float rbfS[4][K_][16];   // 7680 B
    __shared__ float lgS[4][K_ * 8];                  // 3840 B
    __shared__ float distS[4][32];                    //  512 B
    __shared__ float invS[4][8];                      //  128 B
    __shared__ float aggS[4][256];                    // 4096 B
    __shared__ float ybS[4][128];                     // 2048 B
    __shared__ float gbS[4][32];                      //  512 B

    const int bid = blockIdx.x, tid = threadIdx.x;
    const int lane = tid & 63, wid = tid >> 6;
    // XCD swizzle: block bid -> XCD bid&7 gets contiguous target range; wave owns one target
    const int t = ((bid & 7) << 10) | ((bid >> 3) << 2) | wid;
    const int bf = flag[0];

    // persistent per-wave operands (issue early; all L2-hot)
    const f2v* cw = (const f2v*)c_wrb;
    const f2v w0 = cw[0*64+lane],  w1 = cw[1*64+lane],  w2 = cw[2*64+lane],  w3 = cw[3*64+lane];
    const f2v w4 = cw[4*64+lane],  w5 = cw[5*64+lane],  w6 = cw[6*64+lane],  w7 = cw[7*64+lane];
    const f2v w8 = cw[8*64+lane],  w9 = cw[9*64+lane],  wA = cw[10*64+lane], wB = cw[11*64+lane];
    const f2v wC = cw[12*64+lane], wD = cw[13*64+lane], wE = cw[14*64+lane], wF = cw[15*64+lane];
    const f2v avv = ((const f2v*)c_av)[lane];
    const f2v ht  = *(const f2v*)(htgt + ((size_t)t << 7) + (lane << 1));

    // ---- phase 0: edge metadata in lane-slots (lane k<30 holds edge k) ----
    int srcv = 0, dv = 0;
    u64 vmask;
    {
        int src = 0;
        if (lane < K_) {
            src = srcArr[t * K_ + lane];
            src = (src < 0) ? 0 : ((src >= N_) ? (N_ - 1) : src);
        }
        float vx = ldf(trans, src*3+0, bf) - ldf(trans, t*3+0, bf);
        float vy = ldf(trans, src*3+1, bf) - ldf(trans, t*3+1, bf);
        float vz = ldf(trans, src*3+2, bf) - ldf(trans, t*3+2, bf);
        float dist = sqrtf(vx*vx + vy*vy + vz*vz);
        bool valid = isfinite(dist) && (dist > 1e-3f);
        vmask = __ballot(valid);
        srcv = src;
        int d = src - t + 512;
        dv = (d < 0) ? 0 : ((d > 1023) ? 1023 : d);
        if (lane < 32) distS[wid][lane] = dist;
    }

    // ---- rbf: 480 exps across the wave (e = k*16+j) ----
    #pragma unroll
    for (int it = 0; it < 8; ++it) {
        int e = lane + (it << 6);
        if (e < 480) {
            int k = e >> 4, j = e & 15;
            float dd = distS[wid][k];
            float tt = (dd - (float)j * (20.f/15.f)) * 0.8f;
            rbfS[wid][k][j] = __expf(-tt * tt);
        }
    }

    // ---- phase 1: 30 logits, whole wave per edge (lane = channel pair) ----
    #pragma unroll 2
    for (int k = 0; k < K_; ++k) {
        const int src = __builtin_amdgcn_readlane(srcv, k);
        const int d   = __builtin_amdgcn_readlane(dv, k);
        f2v hs = *(const f2v*)(hsrc + ((size_t)src << 7) + (lane << 1));
        f2v pt = *(const f2v*)(ptab + ((size_t)d << 7) + (lane << 1));
        f2v acc = (hs + ht) + pt;
        const float4* rp = (const float4*)(&rbfS[wid][k][0]);
        float4 ra = rp[0], rb = rp[1], rc = rp[2], rd = rp[3];   // broadcast reads
        f2v r0; r0.x = ra.x; r0.y = ra.y;
        f2v r1; r1.x = ra.z; r1.y = ra.w;
        f2v r2; r2.x = rb.x; r2.y = rb.y;
        f2v r3; r3.x = rb.z; r3.y = rb.w;
        f2v r4; r4.x = rc.x; r4.y = rc.y;
        f2v r5; r5.x = rc.z; r5.y = rc.w;
        f2v r6; r6.x = rd.x; r6.y = rd.y;
        f2v r7; r7.x = rd.z; r7.y = rd.w;
        PKFMA_LO(acc, r0, w0); PKFMA_HI(acc, r0, w1);
        PKFMA_LO(acc, r1, w2); PKFMA_HI(acc, r1, w3);
        PKFMA_LO(acc, r2, w4); PKFMA_HI(acc, r2, w5);
        PKFMA_LO(acc, r3, w6); PKFMA_HI(acc, r3, w7);
        PKFMA_LO(acc, r4, w8); PKFMA_HI(acc, r4, w9);
        PKFMA_LO(acc, r5, wA); PKFMA_HI(acc, r5, wB);
        PKFMA_LO(acc, r6, wC); PKFMA_HI(acc, r6, wD);
        PKFMA_LO(acc, r7, wE); PKFMA_HI(acc, r7, wF);
        float part = fsilu(acc.x) * avv.x + fsilu(acc.y) * avv.y;
        DPP_ADD8(part)
        float lg = (part >= 0.f) ? part : 0.2f * part;
        if (!((vmask >> k) & 1ull)) lg = -1e9f;
        lg = (fabsf(lg) < 1e30f) ? lg : -1e9f;
        if ((lane & 7) == 0) lgS[wid][k * 8 + (lane >> 3)] = lg;
    }

    // ---- phase 2: wave-local softmax (8 lanes, one per head) ----
    if (lane < 8) {
        float mx = -1e30f;
        #pragma unroll
        for (int k = 0; k < K_; ++k) mx = fmaxf(mx, lgS[wid][k * 8 + lane]);
        float den = 0.f;
        #pragma unroll
        for (int k = 0; k < K_; ++k) {
            float l = lgS[wid][k * 8 + lane];
            float e = (l > -1e8f) ? __expf(l - mx) : 0.f;
            lgS[wid][k * 8 + lane] = e; den += e;
        }
        invS[wid][lane] = 1.f / (den + 1e-9f);
    }

    // ---- phase 3: V aggregation (lane covers channels 2l,2l+1 and +128) ----
    {
        const int h = (lane & 31) >> 2;      // head of channel 2*lane (same for pair & +128)
        f2v a0; a0.x = 0.f; a0.y = 0.f;
        f2v a1; a1.x = 0.f; a1.y = 0.f;
        #pragma unroll
        for (int k = 0; k < K_; ++k) {
            const int src = __builtin_amdgcn_readlane(srcv, k);
            const float* vr = V + ((size_t)src << 8) + (lane << 1);
            f2v w = splat2(lgS[wid][k * 8 + h]);
            f2v x0 = *(const f2v*)(vr);
            f2v x1 = *(const f2v*)(vr + 128);
            a0 = __builtin_elementwise_fma(w, x0, a0);
            a1 = __builtin_elementwise_fma(w, x1, a1);
        }
        const float inv = invS[wid][h];
        a0.x *= inv; a0.y *= inv; a1.x *= inv; a1.y *= inv;
        *(f2v*)&aggS[wid][(lane << 1)]       = a0;
        *(f2v*)&aggS[wid][(lane << 1) + 128] = a1;
    }

    // ---- phase 4: epilogue, wave-local (2 passes of 64 lanes cover 128 outputs) ----
    #pragma unroll
    for (int p = 0; p < 2; ++p) {
        const int rr = (p << 1) | (lane >> 5);
        const int o  = lane & 31;
        float y = 0.f;
        #pragma unroll
        for (int c = 0; c < 64; ++c) y = fmaf(aggS[wid][rr * 64 + c], Wo[c * 32 + o], y);
        ybS[wid][rr * 32 + o] = y;
    }
    if (lane < 32) {
        float g = 0.f;
        #pragma unroll
        for (int o = 0; o < 32; ++o) g = fmaf(ybS[wid][o], Wg[o * 32 + lane], g);
        gbS[wid][lane] = fsilu(g);
    }
    #pragma unroll
    for (int p = 0; p < 2; ++p) {
        const int rr = (p << 1) | (lane >> 5);
        const int hh = lane & 31;
        float o = 0.f;
        #pragma unroll
        for (int g = 0; g < 32; ++g) o = fmaf(ybS[wid][rr * 32 + g] * gbS[wid][g], W2[g * 32 + hh], o);
        o = (fabsf(o) < 1e30f) ? o : 0.f;
        size_t idx = (size_t)t * 128 + (p << 6) + lane;
        if (bf) ((u16*)outv)[idx] = f2bf(o);
        else    ((float*)outv)[idx] = o;
    }
}

extern "C" void kernel_launch(void* const* d_in, const int* in_sizes, int n_in,
                              void* d_out, int out_size, void* d_ws, size_t ws_size,
                              hipStream_t stream)
{
    const void* rots         = d_in[0];
    const void* trans        = d_in[1];
    const void* node_emb     = d_in[2];
    /* d_in[3] = batch (unused; chains contiguous) */
    const void* x_mask       = d_in[4];
    const void* noising_mask = d_in[5];
    const void* Wa           = d_in[6];
    const void* avec         = d_in[7];
    const void* Wv           = d_in[8];
    const void* Wo           = d_in[9];
    const void* Wg           = d_in[10];
    const void* W2           = d_in[11];

    char* ws = (char*)d_ws;
    int*   flag    = (int*)  (ws + 0);            //        64
    int*   srcArr  = (int*)  (ws + 64);           //   983,040
    float* hsrc    = (float*)(ws + 983104);       // 4,194,304
    float* htgt    = (float*)(ws + 5177408);      // 4,194,304
    float* ptab    = (float*)(ws + 9371712);      //   524,288
    float* V       = (float*)(ws + 9896000);      // 8,388,608
    float* c_wrb   = (float*)(ws + 18284608);     //     8,192
    float* c_av    = (float*)(ws + 18292800);     //       512
    float* c_Wo    = (float*)(ws + 18293312);     //     8,192
    float* c_Wg    = (float*)(ws + 18301504);     //     4,096
    float* c_W2    = (float*)(ws + 18305600);     //     4,096  (end ~18.3 MB)

    hipLaunchKernelGGL(knn_prep_kernel, dim3(2048), dim3(256), 0, stream,
                       rots, trans, node_emb, x_mask, noising_mask,
                       Wa, avec, Wv, Wo, Wg, W2,
                       flag, srcArr, hsrc, htgt, ptab, V,
                       c_wrb, c_av, c_Wo, c_Wg, c_W2);
    hipLaunchKernelGGL(edge_agg_kernel, dim3(2048), dim3(256), 0, stream,
                       trans, srcArr, hsrc, htgt, ptab, V,
                       c_wrb, c_av, c_Wo, c_Wg, c_W2, flag, d_out);
}

// Round 3
// 509.180 us; speedup vs baseline: 1.0130x; 1.0130x over previous
//
#include <hip/hip_runtime.h>
#include <cstdint>

#define B_ 16
#define L_ 512
#define N_ 8192
#define K_ 30
#define E_ (N_*K_)
#define H_ 32
#define C_ 35

typedef uint16_t u16;
typedef uint32_t u32;
typedef unsigned long long u64;
typedef float f2v __attribute__((ext_vector_type(2)));

static __device__ __forceinline__ f2v splat2(float x) { f2v v; v.x = x; v.y = x; return v; }

// adaptive float load: bf16 (u16<<16) or fp32
static __device__ __forceinline__ float ldf(const void* p, int i, int bf) {
    return bf ? __uint_as_float(((u32)((const u16*)p)[i]) << 16)
              : ((const float*)p)[i];
}
static __device__ __forceinline__ float bfu16(u16 x) {
    return __uint_as_float(((u32)x) << 16);
}
// mask load: mode 0 = u8 bool, 1 = int32, 2 = int64 (little-endian low word)
static __device__ __forceinline__ int ldmask(const void* p, int i, int mode) {
    if (mode == 0) return ((const unsigned char*)p)[i] != 0;
    if (mode == 2) return ((const u32*)p)[2*i] != 0;
    return ((const u32*)p)[i] != 0;
}
// f32 -> bf16 RNE
static __device__ __forceinline__ u16 f2bf(float f) {
    u32 x = __float_as_uint(f);
    u32 r = x + 0x7FFFu + ((x >> 16) & 1u);
    return (u16)(r >> 16);
}
// fast silu (~1e-7 rel err)
static __device__ __forceinline__ float fsilu(float x) {
    return x * __builtin_amdgcn_rcpf(1.f + __expf(-x));
}
// wave-uniform-index register broadcast
static __device__ __forceinline__ float RL(float x, int i) {
    return __uint_as_float((u32)__builtin_amdgcn_readlane((int)__float_as_uint(x), i));
}

// wave-level dtype detection (deterministic)
static __device__ __forceinline__ int detect_bf(const void* tr, int lane) {
    const u16* p = (const u16*)tr;
    int cnt = 0;
    for (int i = lane; i < 256; i += 64) {
        u16 v = p[2 * i];
        int e = (v >> 7) & 0xFF;
        if ((e >= 100 && e <= 141) || (v & 0x7FFFu) == 0) cnt++;
    }
    #pragma unroll
    for (int d = 1; d < 64; d <<= 1) cnt += __shfl_xor(cnt, d, 64);
    return cnt >= 192;
}
static __device__ __forceinline__ int detect_mm(const void* xmv, int lane) {
    const u32* xm = (const u32*)xmv;
    int anyBig = 0, oddNZ = 0;
    for (int i = lane; i < 1024; i += 64) {
        u32 w = xm[i];
        if (w & ~1u) anyBig = 1;
        if ((i & 1) && w) oddNZ = 1;
    }
    #pragma unroll
    for (int d = 1; d < 64; d <<= 1) {
        anyBig |= __shfl_xor(anyBig, d, 64);
        oddNZ  |= __shfl_xor(oddNZ, d, 64);
    }
    return anyBig ? 0 : (oddNZ ? 1 : 2);
}

__constant__ float cBB[9] = {-0.525f, 1.363f, 0.f,  0.f, 0.f, 0.f,  1.526f, 0.f, 0.f};

// u32 DPP min step (VALU pipe; d2>=0 -> f32 bit order == u32 order)
#define DPP_UMIN(var, CTRL) \
    { u32 o_ = (u32)__builtin_amdgcn_update_dpp((int)(var), (int)(var), CTRL, 0xF, 0xF, false); \
      (var) = (o_ < (var)) ? o_ : (var); }
#define DPP_UMIN_ALL(var) \
    DPP_UMIN(var, 0x111) DPP_UMIN(var, 0x112) DPP_UMIN(var, 0x114) \
    DPP_UMIN(var, 0x118) DPP_UMIN(var, 0x142) DPP_UMIN(var, 0x143)

// f32 add-reduce over 8-lane group via DPP (bit-identical to shfl_xor 1/2/4 tree)
#define DPP_ADD8(part) \
    part += __uint_as_float((u32)__builtin_amdgcn_update_dpp( \
        (int)__float_as_uint(part), (int)__float_as_uint(part), 0xB1, 0xF, 0xF, false)); \
    part += __uint_as_float((u32)__builtin_amdgcn_update_dpp( \
        (int)__float_as_uint(part), (int)__float_as_uint(part), 0x4E, 0xF, 0xF, false)); \
    part += __uint_as_float((u32)__builtin_amdgcn_update_dpp( \
        (int)__float_as_uint(part), (int)__float_as_uint(part), 0x141, 0xF, 0xF, false));

// packed f32 FMA with op_sel scalar broadcast from one half of rr (bitwise == scalar fma)
#define PKFMA_LO(acc, rr, w) \
    asm("v_pk_fma_f32 %0, %1, %2, %0 op_sel:[0,0,0] op_sel_hi:[0,1,1]" \
        : "+v"(acc) : "v"(rr), "v"(w))
#define PKFMA_HI(acc, rr, w) \
    asm("v_pk_fma_f32 %0, %1, %2, %0 op_sel:[1,0,0] op_sel_hi:[1,1,1]" \
        : "+v"(acc) : "v"(rr), "v"(w))

// =============== kernel A: fused kNN + prep, grid 2048 ====================================
// __launch_bounds__(256,4): VGPR budget 128 -> no scratch spills (R2 post-mortem: the
// (256,8) clamp forced VGPR=32 and 815 MB of spill traffic, 366 us).
// blocks [0,1024)    : kNN, 8 targets/block (wave wid -> targets t0+wid, t0+wid+4)
//                      + weight-convert slice (7 elems/block on tid<7)
// blocks [1024,2048) : prep, 8 nodes/block (wave wid -> nodes nb+wid, nb+wid+4)
//                      + one ptab row (row = bid-1024, cols on tid<128)
__global__ __launch_bounds__(256, 4) void knn_prep_kernel(
    const void* __restrict__ rots, const void* __restrict__ trans,
    const void* __restrict__ node,
    const void* __restrict__ xm, const void* __restrict__ nm,
    const void* __restrict__ Wa, const void* __restrict__ av,
    const void* __restrict__ Wv, const void* __restrict__ Wo,
    const void* __restrict__ Wg, const void* __restrict__ W2,
    int* __restrict__ flag, int* __restrict__ srcArr,
    float* __restrict__ hsrc, float* __restrict__ htgt,
    float* __restrict__ ptab, float* __restrict__ V,
    float* __restrict__ c_wrb, float* __restrict__ c_av,
    float* __restrict__ c_Wo, float* __restrict__ c_Wg, float* __restrict__ c_W2)
{
    __shared__ float sX[L_], sY[L_], sZ[L_];
    __shared__ int flagS[2];
    const int bid = blockIdx.x, tid = threadIdx.x;
    const int lane = tid & 63, wid = tid >> 6;

    if (wid == 0) {
        int bfv = detect_bf(trans, lane);
        int mmv = 0;
        if (bid >= 1024) mmv = detect_mm(xm, lane);
        if (bid == 0 && lane == 0) flag[0] = bfv;   // for kernel B
        if (lane == 0) { flagS[0] = bfv; flagS[1] = mmv; }
    }
    __syncthreads();
    const int bf = flagS[0];

    if (bid < 1024) {
        // ---------------- kNN: 8 targets, 2 per wave ----------------
        const int t0 = bid * 8;
        const int base = t0 & ~511;
        if (bf) {
            const u16* tp = (const u16*)trans;
            for (int i = tid; i < L_; i += 256) {
                sX[i] = bfu16(tp[(base + i) * 3 + 0]);
                sY[i] = bfu16(tp[(base + i) * 3 + 1]);
                sZ[i] = bfu16(tp[(base + i) * 3 + 2]);
            }
        } else {
            const float* tp = (const float*)trans;
            for (int i = tid; i < L_; i += 256) {
                sX[i] = tp[(base + i) * 3 + 0];
                sY[i] = tp[(base + i) * 3 + 1];
                sZ[i] = tp[(base + i) * 3 + 2];
            }
        }
        __syncthreads();

        for (int ti = 0; ti < 2; ++ti) {
            const int t = t0 + wid + (ti << 2);
            const int l = t & 511;
            const float tx = sX[l], ty = sY[l], tz = sZ[l];

            u32 d2b[8];
            #pragma unroll
            for (int i = 0; i < 8; ++i) {
                int j = lane + (i << 6);
                float dx = __fsub_rn(tx, sX[j]);
                float dy = __fsub_rn(ty, sY[j]);
                float dz = __fsub_rn(tz, sZ[j]);
                float d2 = __fadd_rn(__fadd_rn(__fmul_rn(dx, dx), __fmul_rn(dy, dy)), __fmul_rn(dz, dz));
                if (j == l) d2 = __fadd_rn(d2, 1e9f);
                d2b[i] = __float_as_uint(d2);
            }

            int myres = 0;
            for (int k = 0; k < K_; ++k) {
                u32 bb = d2b[0]; int bs = 0;
                #pragma unroll
                for (int i = 1; i < 8; ++i)
                    if (d2b[i] < bb) { bb = d2b[i]; bs = i; }
                u32 m = bb;
                DPP_UMIN_ALL(m)
                u32 gbits = (u32)__builtin_amdgcn_readlane((int)m, 63);
                u64 mask = __ballot(bb == gbits);
                u32 gidx;
                if (__popcll(mask) == 1) {
                    int wl = __ffsll((long long)mask) - 1;
                    gidx = (u32)__builtin_amdgcn_readlane((int)((bs << 6) | lane), wl);
                } else {
                    u32 cand = (bb == gbits) ? (u32)((bs << 6) | lane) : 0xFFFFFFFFu;
                    DPP_UMIN_ALL(cand)
                    gidx = (u32)__builtin_amdgcn_readlane((int)cand, 63);
                }
                if (lane == (u32)k) myres = (int)(gidx & 511u);
                if ((gidx & 63u) == (u32)lane) {
                    int ws = (int)(gidx >> 6);
                    #pragma unroll
                    for (int i = 0; i < 8; ++i)
                        if (ws == i) d2b[i] = 0xFFFFFFFFu;
                }
            }
            if (lane < K_) srcArr[t * K_ + lane] = base + myres;
        }

        // weight-convert slice: 7 elems per block covers 6272 over 1024 blocks
        if (tid < 7) {
            int i = bid * 7 + tid;
            if (i < 6272) {
                if      (i < 2048) c_wrb[i]        = ldf(Wa, 70 * 128 + i, bf);
                else if (i < 2176) c_av[i - 2048]  = ldf(av, i - 2048, bf);
                else if (i < 4224) c_Wo[i - 2176]  = ldf(Wo, i - 2176, bf);
                else if (i < 5248) c_Wg[i - 4224]  = ldf(Wg, i - 4224, bf);
                else               c_W2[i - 5248]  = ldf(W2, i - 5248, bf);
            }
        }

    } else {
        // ---------------- prep: 8 nodes, 2 per wave ----------------
        const int mm = flagS[1];
        const int nb = (bid - 1024) * 8;

        for (int ni = 0; ni < 2; ++ni) {
            const int n = nb + wid + (ni << 2);

            float eA, eB, eC = 0.f;
            {
                int s = lane;                       // 0..63
                int r = s / 35, c = s - r * 35;
                if (c < H_)      eA = ldf(node, n * 128 + r * 32 + c, bf);
                else if (r == 0) eA = (c == 34) ? ((ldmask(nm, n, mm) && !ldmask(xm, n, mm)) ? 1.f : 0.f) : 0.f;
                else {
                    int i = r - 1, a = c - 32;
                    eA = ldf(rots, n*9 + i*3 + 0, bf) * cBB[a*3 + 0]
                       + ldf(rots, n*9 + i*3 + 1, bf) * cBB[a*3 + 1]
                       + ldf(rots, n*9 + i*3 + 2, bf) * cBB[a*3 + 2];
                }
                s = lane + 64;                      // 64..127
                r = s / 35; c = s - r * 35;
                if (c < H_)      eB = ldf(node, n * 128 + r * 32 + c, bf);
                else {
                    int i = r - 1, a = c - 32;
                    eB = ldf(rots, n*9 + i*3 + 0, bf) * cBB[a*3 + 0]
                       + ldf(rots, n*9 + i*3 + 1, bf) * cBB[a*3 + 1]
                       + ldf(rots, n*9 + i*3 + 2, bf) * cBB[a*3 + 2];
                }
                if (lane < 12) {
                    s = lane + 128;                 // 128..139
                    r = s / 35; c = s - r * 35;
                    if (c < H_)      eC = ldf(node, n * 128 + r * 32 + c, bf);
                    else {
                        int i = r - 1, a = c - 32;
                        eC = ldf(rots, n*9 + i*3 + 0, bf) * cBB[a*3 + 0]
                           + ldf(rots, n*9 + i*3 + 1, bf) * cBB[a*3 + 1]
                           + ldf(rots, n*9 + i*3 + 2, bf) * cBB[a*3 + 2];
                    }
                }
            }

            float a0 = 0.f, a1 = 0.f, b0 = 0.f, b1 = 0.f;
            float v0 = 0.f, v1 = 0.f, v2 = 0.f, v3 = 0.f;
            if (bf) {
                const u16* wa = (const u16*)Wa;
                const u16* wv = (const u16*)Wv;
                #pragma unroll
                for (int i = 0; i < 35; ++i) {
                    float ei = RL(eA, i);
                    a0 = fmaf(ei, bfu16(wa[i * 128 + lane]),        a0);
                    a1 = fmaf(ei, bfu16(wa[i * 128 + lane + 64]),   a1);
                    b0 = fmaf(ei, bfu16(wa[(35 + i) * 128 + lane]),      b0);
                    b1 = fmaf(ei, bfu16(wa[(35 + i) * 128 + lane + 64]), b1);
                }
                #pragma unroll
                for (int cp = 0; cp < 35; ++cp) {
                    float w = bfu16(wv[cp * 64 + lane]);
                    float e1 = (35 + cp < 64) ? RL(eA, 35 + cp) : RL(eB, cp - 29);
                    float e3 = (cp < 23) ? RL(eB, 41 + cp) : RL(eC, cp - 23);
                    v0 = fmaf(RL(eA, cp), w, v0);
                    v1 = fmaf(e1, w, v1);
                    v2 = fmaf(RL(eB, cp + 6), w, v2);
                    v3 = fmaf(e3, w, v3);
                }
            } else {
                const float* wa = (const float*)Wa;
                const float* wv = (const float*)Wv;
                #pragma unroll
                for (int i = 0; i < 35; ++i) {
                    float ei = RL(eA, i);
                    a0 = fmaf(ei, wa[i * 128 + lane],        a0);
                    a1 = fmaf(ei, wa[i * 128 + lane + 64],   a1);
                    b0 = fmaf(ei, wa[(35 + i) * 128 + lane],      b0);
                    b1 = fmaf(ei, wa[(35 + i) * 128 + lane + 64], b1);
                }
                #pragma unroll
                for (int cp = 0; cp < 35; ++cp) {
                    float w = wv[cp * 64 + lane];
                    float e1 = (35 + cp < 64) ? RL(eA, 35 + cp) : RL(eB, cp - 29);
                    float e3 = (cp < 23) ? RL(eB, 41 + cp) : RL(eC, cp - 23);
                    v0 = fmaf(RL(eA, cp), w, v0);
                    v1 = fmaf(e1, w, v1);
                    v2 = fmaf(RL(eB, cp + 6), w, v2);
                    v3 = fmaf(e3, w, v3);
                }
            }
            hsrc[(size_t)n * 128 + lane]      = a0;
            hsrc[(size_t)n * 128 + lane + 64] = a1;
            htgt[(size_t)n * 128 + lane]      = b0;
            htgt[(size_t)n * 128 + lane + 64] = b1;
            float* vp = V + (size_t)n * 256 + lane;
            vp[0] = v0; vp[64] = v1; vp[128] = v2; vp[192] = v3;
        }

        // one ptab row per prep block: row d = bid-1024, cols tid<128
        const int d = bid - 1024;
        if (tid < 128) {
            float dd = (float)(d - 512);
            float acc = 0.f;
            if (bf) {
                const u16* wa = (const u16*)Wa;
                #pragma unroll
                for (int q = 0; q < 8; ++q) {
                    float fr = expf((float)(2 * q) * (-0.5756462732485115f)); // -ln(1e4)/16
                    float ang = dd * fr;
                    acc = fmaf(cosf(ang), bfu16(wa[(86 + q) * 128 + tid]), acc);
                    acc = fmaf(sinf(ang), bfu16(wa[(94 + q) * 128 + tid]), acc);
                }
            } else {
                const float* wa = (const float*)Wa;
                #pragma unroll
                for (int q = 0; q < 8; ++q) {
                    float fr = expf((float)(2 * q) * (-0.5756462732485115f));
                    float ang = dd * fr;
                    acc = fmaf(cosf(ang), wa[(86 + q) * 128 + tid], acc);
                    acc = fmaf(sinf(ang), wa[(94 + q) * 128 + tid], acc);
                }
            }
            ptab[(size_t)d * 128 + tid] = acc;
        }
    }
}

// =============== kernel B: wave-per-target, barrier-free, grid 2048 ========================
// __launch_bounds__(256,4): VGPR budget 128 -> 16 GEMV weight f2v's stay register-resident.
// Wave wid of block bid owns target t end-to-end; all LDS wave-private; no __syncthreads.
__global__ __launch_bounds__(256, 4) void edge_agg_kernel(
    const void* __restrict__ trans, const int* __restrict__ srcArr,
    const float* __restrict__ hsrc, const float* __restrict__ htgt,
    const float* __restrict__ ptab, const float* __restrict__ V,
    const float* __restrict__ c_wrb, const float* __restrict__ c_av,
    const float* __restrict__ Wo, const float* __restrict__ Wg,
    const float* __restrict__ W2,
    const int* __restrict__ flag, void* __restrict__ outv)
{
    __shared__ __align__(16) float rbfS[4][K_][16];   // 7680 B
    __shared__ float lgS[4][K_ * 8];                  // 3840 B
    __shared__ float distS[4][32];                    //  512 B
    __shared__ float invS[4][8];                      //  128 B
    __shared__ float aggS[4][256];                    // 4096 B
    __shared__ float ybS[4][128];                     // 2048 B
    __shared__ float gbS[4][32];                      //  512 B

    const int bid = blockIdx.x, tid = threadIdx.x;
    const int lane = tid & 63, wid = tid >> 6;
    // XCD swizzle: block bid -> XCD bid&7 gets contiguous target range; wave owns one target
    const int t = ((bid & 7) << 10) | ((bid >> 3) << 2) | wid;
    const int bf = flag[0];

    // persistent per-wave operands (issue early; all L2-hot)
    const f2v* cw = (const f2v*)c_wrb;
    const f2v w0 = cw[0*64+lane],  w1 = cw[1*64+lane],  w2 = cw[2*64+lane],  w3 = cw[3*64+lane];
    const f2v w4 = cw[4*64+lane],  w5 = cw[5*64+lane],  w6 = cw[6*64+lane],  w7 = cw[7*64+lane];
    const f2v w8 = cw[8*64+lane],  w9 = cw[9*64+lane],  wA = cw[10*64+lane], wB = cw[11*64+lane];
    const f2v wC = cw[12*64+lane], wD = cw[13*64+lane], wE = cw[14*64+lane], wF = cw[15*64+lane];
    const f2v avv = ((const f2v*)c_av)[lane];
    const f2v ht  = *(const f2v*)(htgt + ((size_t)t << 7) + (lane << 1));

    // ---- phase 0: edge metadata in lane-slots (lane k<30 holds edge k) ----
    int srcv = 0, dv = 0;
    u64 vmask;
    {
        int src = 0;
        if (lane < K_) {
            src = srcArr[t * K_ + lane];
            src = (src < 0) ? 0 : ((src >= N_) ? (N_ - 1) : src);
        }
        float vx = ldf(trans, src*3+0, bf) - ldf(trans, t*3+0, bf);
        float vy = ldf(trans, src*3+1, bf) - ldf(trans, t*3+1, bf);
        float vz = ldf(trans, src*3+2, bf) - ldf(trans, t*3+2, bf);
        float dist = sqrtf(vx*vx + vy*vy + vz*vz);
        bool valid = isfinite(dist) && (dist > 1e-3f);
        vmask = __ballot(valid);
        srcv = src;
        int d = src - t + 512;
        dv = (d < 0) ? 0 : ((d > 1023) ? 1023 : d);
        if (lane < 32) distS[wid][lane] = dist;
    }

    // ---- rbf: 480 exps across the wave (e = k*16+j) ----
    #pragma unroll
    for (int it = 0; it < 8; ++it) {
        int e = lane + (it << 6);
        if (e < 480) {
            int k = e >> 4, j = e & 15;
            float dd = distS[wid][k];
            float tt = (dd - (float)j * (20.f/15.f)) * 0.8f;
            rbfS[wid][k][j] = __expf(-tt * tt);
        }
    }

    // ---- phase 1: 30 logits, whole wave per edge (lane = channel pair) ----
    #pragma unroll 2
    for (int k = 0; k < K_; ++k) {
        const int src = __builtin_amdgcn_readlane(srcv, k);
        const int d   = __builtin_amdgcn_readlane(dv, k);
        f2v hs = *(const f2v*)(hsrc + ((size_t)src << 7) + (lane << 1));
        f2v pt = *(const f2v*)(ptab + ((size_t)d << 7) + (lane << 1));
        f2v acc = (hs + ht) + pt;
        const float4* rp = (const float4*)(&rbfS[wid][k][0]);
        float4 ra = rp[0], rb = rp[1], rc = rp[2], rd = rp[3];   // broadcast reads
        f2v r0; r0.x = ra.x; r0.y = ra.y;
        f2v r1; r1.x = ra.z; r1.y = ra.w;
        f2v r2; r2.x = rb.x; r2.y = rb.y;
        f2v r3; r3.x = rb.z; r3.y = rb.w;
        f2v r4; r4.x = rc.x; r4.y = rc.y;
        f2v r5; r5.x = rc.z; r5.y = rc.w;
        f2v r6; r6.x = rd.x; r6.y = rd.y;
        f2v r7; r7.x = rd.z; r7.y = rd.w;
        PKFMA_LO(acc, r0, w0); PKFMA_HI(acc, r0, w1);
        PKFMA_LO(acc, r1, w2); PKFMA_HI(acc, r1, w3);
        PKFMA_LO(acc, r2, w4); PKFMA_HI(acc, r2, w5);
        PKFMA_LO(acc, r3, w6); PKFMA_HI(acc, r3, w7);
        PKFMA_LO(acc, r4, w8); PKFMA_HI(acc, r4, w9);
        PKFMA_LO(acc, r5, wA); PKFMA_HI(acc, r5, wB);
        PKFMA_LO(acc, r6, wC); PKFMA_HI(acc, r6, wD);
        PKFMA_LO(acc, r7, wE); PKFMA_HI(acc, r7, wF);
        float part = fsilu(acc.x) * avv.x + fsilu(acc.y) * avv.y;
        DPP_ADD8(part)
        float lg = (part >= 0.f) ? part : 0.2f * part;
        if (!((vmask >> k) & 1ull)) lg = -1e9f;
        lg = (fabsf(lg) < 1e30f) ? lg : -1e9f;
        if ((lane & 7) == 0) lgS[wid][k * 8 + (lane >> 3)] = lg;
    }

    // ---- phase 2: wave-local softmax (8 lanes, one per head) ----
    if (lane < 8) {
        float mx = -1e30f;
        #pragma unroll
        for (int k = 0; k < K_; ++k) mx = fmaxf(mx, lgS[wid][k * 8 + lane]);
        float den = 0.f;
        #pragma unroll
        for (int k = 0; k < K_; ++k) {
            float l = lgS[wid][k * 8 + lane];
            float e = (l > -1e8f) ? __expf(l - mx) : 0.f;
            lgS[wid][k * 8 + lane] = e; den += e;
        }
        invS[wid][lane] = 1.f / (den + 1e-9f);
    }

    // ---- phase 3: V aggregation (lane covers channels 2l,2l+1 and +128) ----
    {
        const int h = (lane & 31) >> 2;      // head of channel 2*lane (same for pair & +128)
        f2v a0; a0.x = 0.f; a0.y = 0.f;
        f2v a1; a1.x = 0.f; a1.y = 0.f;
        #pragma unroll
        for (int k = 0; k < K_; ++k) {
            const int src = __builtin_amdgcn_readlane(srcv, k);
            const float* vr = V + ((size_t)src << 8) + (lane << 1);
            f2v w = splat2(lgS[wid][k * 8 + h]);
            f2v x0 = *(const f2v*)(vr);
            f2v x1 = *(const f2v*)(vr + 128);
            a0 = __builtin_elementwise_fma(w, x0, a0);
            a1 = __builtin_elementwise_fma(w, x1, a1);
        }
        const float inv = invS[wid][h];
        a0.x *= inv; a0.y *= inv; a1.x *= inv; a1.y *= inv;
        *(f2v*)&aggS[wid][(lane << 1)]       = a0;
        *(f2v*)&aggS[wid][(lane << 1) + 128] = a1;
    }

    // ---- phase 4: epilogue, wave-local (2 passes of 64 lanes cover 128 outputs) ----
    #pragma unroll
    for (int p = 0; p < 2; ++p) {
        const int rr = (p << 1) | (lane >> 5);
        const int o  = lane & 31;
        float y = 0.f;
        #pragma unroll
        for (int c = 0; c < 64; ++c) y = fmaf(aggS[wid][rr * 64 + c], Wo[c * 32 + o], y);
        ybS[wid][rr * 32 + o] = y;
    }
    if (lane < 32) {
        float g = 0.f;
        #pragma unroll
        for (int o = 0; o < 32; ++o) g = fmaf(ybS[wid][o], Wg[o * 32 + lane], g);
        gbS[wid][lane] = fsilu(g);
    }
    #pragma unroll
    for (int p = 0; p < 2; ++p) {
        const int rr = (p << 1) | (lane >> 5);
        const int hh = lane & 31;
        float o = 0.f;
        #pragma unroll
        for (int g = 0; g < 32; ++g) o = fmaf(ybS[wid][rr * 32 + g] * gbS[wid][g], W2[g * 32 + hh], o);
        o = (fabsf(o) < 1e30f) ? o : 0.f;
        size_t idx = (size_t)t * 128 + (p << 6) + lane;
        if (bf) ((u16*)outv)[idx] = f2bf(o);
        else    ((float*)outv)[idx] = o;
    }
}

extern "C" void kernel_launch(void* const* d_in, const int* in_sizes, int n_in,
                              void* d_out, int out_size, void* d_ws, size_t ws_size,
                              hipStream_t stream)
{
    const void* rots         = d_in[0];
    const void* trans        = d_in[1];
    const void* node_emb     = d_in[2];
    /* d_in[3] = batch (unused; chains contiguous) */
    const void* x_mask       = d_in[4];
    const void* noising_mask = d_in[5];
    const void* Wa           = d_in[6];
    const void* avec         = d_in[7];
    const void* Wv           = d_in[8];
    const void* Wo           = d_in[9];
    const void* Wg           = d_in[10];
    const void* W2           = d_in[11];

    char* ws = (char*)d_ws;
    int*   flag    = (int*)  (ws + 0);            //        64
    int*   srcArr  = (int*)  (ws + 64);           //   983,040
    float* hsrc    = (float*)(ws + 983104);       // 4,194,304
    float* htgt    = (float*)(ws + 5177408);      // 4,194,304
    float* ptab    = (float*)(ws + 9371712);      //   524,288
    float* V       = (float*)(ws + 9896000);      // 8,388,608
    float* c_wrb   = (float*)(ws + 18284608);     //     8,192
    float* c_av    = (float*)(ws + 18292800);     //       512
    float* c_Wo    = (float*)(ws + 18293312);     //     8,192
    float* c_Wg    = (float*)(ws + 18301504);     //     4,096
    float* c_W2    = (float*)(ws + 18305600);     //     4,096  (end ~18.3 MB)

    hipLaunchKernelGGL(knn_prep_kernel, dim3(2048), dim3(256), 0, stream,
                       rots, trans, node_emb, x_mask, noising_mask,
                       Wa, avec, Wv, Wo, Wg, W2,
                       flag, srcArr, hsrc, htgt, ptab, V,
                       c_wrb, c_av, c_Wo, c_Wg, c_W2);
    hipLaunchKernelGGL(edge_agg_kernel, dim3(2048), dim3(256), 0, stream,
                       trans, srcArr, hsrc, htgt, ptab, V,
                       c_wrb, c_av, c_Wo, c_Wg, c_W2, flag, d_out);
}

// Round 4
// 367.590 us; speedup vs baseline: 1.4032x; 1.3852x over previous
//
#include <hip/hip_runtime.h>
#include <cstdint>

#define B_ 16
#define L_ 512
#define N_ 8192
#define K_ 30
#define E_ (N_*K_)
#define H_ 32
#define C_ 35

typedef uint16_t u16;
typedef uint32_t u32;
typedef unsigned long long u64;
typedef float f2v __attribute__((ext_vector_type(2)));

static __device__ __forceinline__ f2v splat2(float x) { f2v v; v.x = x; v.y = x; return v; }

// adaptive float load: bf16 (u16<<16) or fp32
static __device__ __forceinline__ float ldf(const void* p, int i, int bf) {
    return bf ? __uint_as_float(((u32)((const u16*)p)[i]) << 16)
              : ((const float*)p)[i];
}
static __device__ __forceinline__ float bfu16(u16 x) {
    return __uint_as_float(((u32)x) << 16);
}
// mask load: mode 0 = u8 bool, 1 = int32, 2 = int64 (little-endian low word)
static __device__ __forceinline__ int ldmask(const void* p, int i, int mode) {
    if (mode == 0) return ((const unsigned char*)p)[i] != 0;
    if (mode == 2) return ((const u32*)p)[2*i] != 0;
    return ((const u32*)p)[i] != 0;
}
// f32 -> bf16 RNE
static __device__ __forceinline__ u16 f2bf(float f) {
    u32 x = __float_as_uint(f);
    u32 r = x + 0x7FFFu + ((x >> 16) & 1u);
    return (u16)(r >> 16);
}
// fast silu (~1e-7 rel err)
static __device__ __forceinline__ float fsilu(float x) {
    return x * __builtin_amdgcn_rcpf(1.f + __expf(-x));
}
// wave-uniform-index register broadcast
static __device__ __forceinline__ float RL(float x, int i) {
    return __uint_as_float((u32)__builtin_amdgcn_readlane((int)__float_as_uint(x), i));
}

// wave-level dtype detection (deterministic)
static __device__ __forceinline__ int detect_bf(const void* tr, int lane) {
    const u16* p = (const u16*)tr;
    int cnt = 0;
    for (int i = lane; i < 256; i += 64) {
        u16 v = p[2 * i];
        int e = (v >> 7) & 0xFF;
        if ((e >= 100 && e <= 141) || (v & 0x7FFFu) == 0) cnt++;
    }
    #pragma unroll
    for (int d = 1; d < 64; d <<= 1) cnt += __shfl_xor(cnt, d, 64);
    return cnt >= 192;
}
static __device__ __forceinline__ int detect_mm(const void* xmv, int lane) {
    const u32* xm = (const u32*)xmv;
    int anyBig = 0, oddNZ = 0;
    for (int i = lane; i < 1024; i += 64) {
        u32 w = xm[i];
        if (w & ~1u) anyBig = 1;
        if ((i & 1) && w) oddNZ = 1;
    }
    #pragma unroll
    for (int d = 1; d < 64; d <<= 1) {
        anyBig |= __shfl_xor(anyBig, d, 64);
        oddNZ  |= __shfl_xor(oddNZ, d, 64);
    }
    return anyBig ? 0 : (oddNZ ? 1 : 2);
}

__constant__ float cBB[9] = {-0.525f, 1.363f, 0.f,  0.f, 0.f, 0.f,  1.526f, 0.f, 0.f};

// u32 DPP min step (VALU pipe; d2>=0 -> f32 bit order == u32 order)
#define DPP_UMIN(var, CTRL) \
    { u32 o_ = (u32)__builtin_amdgcn_update_dpp((int)(var), (int)(var), CTRL, 0xF, 0xF, false); \
      (var) = (o_ < (var)) ? o_ : (var); }
#define DPP_UMIN_ALL(var) \
    DPP_UMIN(var, 0x111) DPP_UMIN(var, 0x112) DPP_UMIN(var, 0x114) \
    DPP_UMIN(var, 0x118) DPP_UMIN(var, 0x142) DPP_UMIN(var, 0x143)

// f32 add-reduce over 8-lane group via DPP (bit-identical to shfl_xor 1/2/4 tree)
#define DPP_ADD8(part) \
    part += __uint_as_float((u32)__builtin_amdgcn_update_dpp( \
        (int)__float_as_uint(part), (int)__float_as_uint(part), 0xB1, 0xF, 0xF, false)); \
    part += __uint_as_float((u32)__builtin_amdgcn_update_dpp( \
        (int)__float_as_uint(part), (int)__float_as_uint(part), 0x4E, 0xF, 0xF, false)); \
    part += __uint_as_float((u32)__builtin_amdgcn_update_dpp( \
        (int)__float_as_uint(part), (int)__float_as_uint(part), 0x141, 0xF, 0xF, false));

// packed f32 FMA with op_sel scalar broadcast from one half of rr (bitwise == scalar fma)
#define PKFMA_LO(acc, rr, w) \
    asm("v_pk_fma_f32 %0, %1, %2, %0 op_sel:[0,0,0] op_sel_hi:[0,1,1]" \
        : "+v"(acc) : "v"(rr), "v"(w))
#define PKFMA_HI(acc, rr, w) \
    asm("v_pk_fma_f32 %0, %1, %2, %0 op_sel:[1,0,0] op_sel_hi:[1,1,1]" \
        : "+v"(acc) : "v"(rr), "v"(w))

// =============== kernel A: fused kNN + prep, grid 2048 ====================================
// NO min-waves clamp: R2/R3 post-mortem showed __launch_bounds__(256,{8,4}) makes the
// allocator settle at half the arch-VGPR budget (32/64) and spill ~700 MB of scratch
// (368 us, VALUBusy 9%). Plain (256) was spill-free in R0/R1.
// blocks [0,1024)    : kNN, 8 targets/block (wave wid -> targets t0+wid, t0+wid+4)
//                      + weight-convert slice (7 elems/block on tid<7)
// blocks [1024,2048) : prep, 8 nodes/block (wave wid -> nodes nb+wid, nb+wid+4)
//                      + one ptab row (row = bid-1024, cols on tid<128)
__global__ __launch_bounds__(256) void knn_prep_kernel(
    const void* __restrict__ rots, const void* __restrict__ trans,
    const void* __restrict__ node,
    const void* __restrict__ xm, const void* __restrict__ nm,
    const void* __restrict__ Wa, const void* __restrict__ av,
    const void* __restrict__ Wv, const void* __restrict__ Wo,
    const void* __restrict__ Wg, const void* __restrict__ W2,
    int* __restrict__ flag, int* __restrict__ srcArr,
    float* __restrict__ hsrc, float* __restrict__ htgt,
    float* __restrict__ ptab, float* __restrict__ V,
    float* __restrict__ c_wrb, float* __restrict__ c_av,
    float* __restrict__ c_Wo, float* __restrict__ c_Wg, float* __restrict__ c_W2)
{
    __shared__ float sX[L_], sY[L_], sZ[L_];
    __shared__ int flagS[2];
    const int bid = blockIdx.x, tid = threadIdx.x;
    const int lane = tid & 63, wid = tid >> 6;

    if (wid == 0) {
        int bfv = detect_bf(trans, lane);
        int mmv = 0;
        if (bid >= 1024) mmv = detect_mm(xm, lane);
        if (bid == 0 && lane == 0) flag[0] = bfv;   // for kernel B
        if (lane == 0) { flagS[0] = bfv; flagS[1] = mmv; }
    }
    __syncthreads();
    const int bf = flagS[0];

    if (bid < 1024) {
        // ---------------- kNN: 8 targets, 2 per wave ----------------
        const int t0 = bid * 8;
        const int base = t0 & ~511;
        if (bf) {
            const u16* tp = (const u16*)trans;
            for (int i = tid; i < L_; i += 256) {
                sX[i] = bfu16(tp[(base + i) * 3 + 0]);
                sY[i] = bfu16(tp[(base + i) * 3 + 1]);
                sZ[i] = bfu16(tp[(base + i) * 3 + 2]);
            }
        } else {
            const float* tp = (const float*)trans;
            for (int i = tid; i < L_; i += 256) {
                sX[i] = tp[(base + i) * 3 + 0];
                sY[i] = tp[(base + i) * 3 + 1];
                sZ[i] = tp[(base + i) * 3 + 2];
            }
        }
        __syncthreads();

        for (int ti = 0; ti < 2; ++ti) {
            const int t = t0 + wid + (ti << 2);
            const int l = t & 511;
            const float tx = sX[l], ty = sY[l], tz = sZ[l];

            u32 d2b[8];
            #pragma unroll
            for (int i = 0; i < 8; ++i) {
                int j = lane + (i << 6);
                float dx = __fsub_rn(tx, sX[j]);
                float dy = __fsub_rn(ty, sY[j]);
                float dz = __fsub_rn(tz, sZ[j]);
                float d2 = __fadd_rn(__fadd_rn(__fmul_rn(dx, dx), __fmul_rn(dy, dy)), __fmul_rn(dz, dz));
                if (j == l) d2 = __fadd_rn(d2, 1e9f);
                d2b[i] = __float_as_uint(d2);
            }

            int myres = 0;
            for (int k = 0; k < K_; ++k) {
                u32 bb = d2b[0]; int bs = 0;
                #pragma unroll
                for (int i = 1; i < 8; ++i)
                    if (d2b[i] < bb) { bb = d2b[i]; bs = i; }
                u32 m = bb;
                DPP_UMIN_ALL(m)
                u32 gbits = (u32)__builtin_amdgcn_readlane((int)m, 63);
                u64 mask = __ballot(bb == gbits);
                u32 gidx;
                if (__popcll(mask) == 1) {
                    int wl = __ffsll((long long)mask) - 1;
                    gidx = (u32)__builtin_amdgcn_readlane((int)((bs << 6) | lane), wl);
                } else {
                    u32 cand = (bb == gbits) ? (u32)((bs << 6) | lane) : 0xFFFFFFFFu;
                    DPP_UMIN_ALL(cand)
                    gidx = (u32)__builtin_amdgcn_readlane((int)cand, 63);
                }
                if (lane == (u32)k) myres = (int)(gidx & 511u);
                if ((gidx & 63u) == (u32)lane) {
                    int ws = (int)(gidx >> 6);
                    #pragma unroll
                    for (int i = 0; i < 8; ++i)
                        if (ws == i) d2b[i] = 0xFFFFFFFFu;
                }
            }
            if (lane < K_) srcArr[t * K_ + lane] = base + myres;
        }

        // weight-convert slice: 7 elems per block covers 6272 over 1024 blocks
        if (tid < 7) {
            int i = bid * 7 + tid;
            if (i < 6272) {
                if      (i < 2048) c_wrb[i]        = ldf(Wa, 70 * 128 + i, bf);
                else if (i < 2176) c_av[i - 2048]  = ldf(av, i - 2048, bf);
                else if (i < 4224) c_Wo[i - 2176]  = ldf(Wo, i - 2176, bf);
                else if (i < 5248) c_Wg[i - 4224]  = ldf(Wg, i - 4224, bf);
                else               c_W2[i - 5248]  = ldf(W2, i - 5248, bf);
            }
        }

    } else {
        // ---------------- prep: 8 nodes, 2 per wave ----------------
        const int mm = flagS[1];
        const int nb = (bid - 1024) * 8;

        for (int ni = 0; ni < 2; ++ni) {
            const int n = nb + wid + (ni << 2);

            float eA, eB, eC = 0.f;
            {
                int s = lane;                       // 0..63
                int r = s / 35, c = s - r * 35;
                if (c < H_)      eA = ldf(node, n * 128 + r * 32 + c, bf);
                else if (r == 0) eA = (c == 34) ? ((ldmask(nm, n, mm) && !ldmask(xm, n, mm)) ? 1.f : 0.f) : 0.f;
                else {
                    int i = r - 1, a = c - 32;
                    eA = ldf(rots, n*9 + i*3 + 0, bf) * cBB[a*3 + 0]
                       + ldf(rots, n*9 + i*3 + 1, bf) * cBB[a*3 + 1]
                       + ldf(rots, n*9 + i*3 + 2, bf) * cBB[a*3 + 2];
                }
                s = lane + 64;                      // 64..127
                r = s / 35; c = s - r * 35;
                if (c < H_)      eB = ldf(node, n * 128 + r * 32 + c, bf);
                else {
                    int i = r - 1, a = c - 32;
                    eB = ldf(rots, n*9 + i*3 + 0, bf) * cBB[a*3 + 0]
                       + ldf(rots, n*9 + i*3 + 1, bf) * cBB[a*3 + 1]
                       + ldf(rots, n*9 + i*3 + 2, bf) * cBB[a*3 + 2];
                }
                if (lane < 12) {
                    s = lane + 128;                 // 128..139
                    r = s / 35; c = s - r * 35;
                    if (c < H_)      eC = ldf(node, n * 128 + r * 32 + c, bf);
                    else {
                        int i = r - 1, a = c - 32;
                        eC = ldf(rots, n*9 + i*3 + 0, bf) * cBB[a*3 + 0]
                           + ldf(rots, n*9 + i*3 + 1, bf) * cBB[a*3 + 1]
                           + ldf(rots, n*9 + i*3 + 2, bf) * cBB[a*3 + 2];
                    }
                }
            }

            float a0 = 0.f, a1 = 0.f, b0 = 0.f, b1 = 0.f;
            float v0 = 0.f, v1 = 0.f, v2 = 0.f, v3 = 0.f;
            if (bf) {
                const u16* wa = (const u16*)Wa;
                const u16* wv = (const u16*)Wv;
                #pragma unroll
                for (int i = 0; i < 35; ++i) {
                    float ei = RL(eA, i);
                    a0 = fmaf(ei, bfu16(wa[i * 128 + lane]),        a0);
                    a1 = fmaf(ei, bfu16(wa[i * 128 + lane + 64]),   a1);
                    b0 = fmaf(ei, bfu16(wa[(35 + i) * 128 + lane]),      b0);
                    b1 = fmaf(ei, bfu16(wa[(35 + i) * 128 + lane + 64]), b1);
                }
                #pragma unroll
                for (int cp = 0; cp < 35; ++cp) {
                    float w = bfu16(wv[cp * 64 + lane]);
                    float e1 = (35 + cp < 64) ? RL(eA, 35 + cp) : RL(eB, cp - 29);
                    float e3 = (cp < 23) ? RL(eB, 41 + cp) : RL(eC, cp - 23);
                    v0 = fmaf(RL(eA, cp), w, v0);
                    v1 = fmaf(e1, w, v1);
                    v2 = fmaf(RL(eB, cp + 6), w, v2);
                    v3 = fmaf(e3, w, v3);
                }
            } else {
                const float* wa = (const float*)Wa;
                const float* wv = (const float*)Wv;
                #pragma unroll
                for (int i = 0; i < 35; ++i) {
                    float ei = RL(eA, i);
                    a0 = fmaf(ei, wa[i * 128 + lane],        a0);
                    a1 = fmaf(ei, wa[i * 128 + lane + 64],   a1);
                    b0 = fmaf(ei, wa[(35 + i) * 128 + lane],      b0);
                    b1 = fmaf(ei, wa[(35 + i) * 128 + lane + 64], b1);
                }
                #pragma unroll
                for (int cp = 0; cp < 35; ++cp) {
                    float w = wv[cp * 64 + lane];
                    float e1 = (35 + cp < 64) ? RL(eA, 35 + cp) : RL(eB, cp - 29);
                    float e3 = (cp < 23) ? RL(eB, 41 + cp) : RL(eC, cp - 23);
                    v0 = fmaf(RL(eA, cp), w, v0);
                    v1 = fmaf(e1, w, v1);
                    v2 = fmaf(RL(eB, cp + 6), w, v2);
                    v3 = fmaf(e3, w, v3);
                }
            }
            hsrc[(size_t)n * 128 + lane]      = a0;
            hsrc[(size_t)n * 128 + lane + 64] = a1;
            htgt[(size_t)n * 128 + lane]      = b0;
            htgt[(size_t)n * 128 + lane + 64] = b1;
            float* vp = V + (size_t)n * 256 + lane;
            vp[0] = v0; vp[64] = v1; vp[128] = v2; vp[192] = v3;
        }

        // one ptab row per prep block: row d = bid-1024, cols tid<128
        const int d = bid - 1024;
        if (tid < 128) {
            float dd = (float)(d - 512);
            float acc = 0.f;
            if (bf) {
                const u16* wa = (const u16*)Wa;
                #pragma unroll
                for (int q = 0; q < 8; ++q) {
                    float fr = expf((float)(2 * q) * (-0.5756462732485115f)); // -ln(1e4)/16
                    float ang = dd * fr;
                    acc = fmaf(cosf(ang), bfu16(wa[(86 + q) * 128 + tid]), acc);
                    acc = fmaf(sinf(ang), bfu16(wa[(94 + q) * 128 + tid]), acc);
                }
            } else {
                const float* wa = (const float*)Wa;
                #pragma unroll
                for (int q = 0; q < 8; ++q) {
                    float fr = expf((float)(2 * q) * (-0.5756462732485115f));
                    float ang = dd * fr;
                    acc = fmaf(cosf(ang), wa[(86 + q) * 128 + tid], acc);
                    acc = fmaf(sinf(ang), wa[(94 + q) * 128 + tid], acc);
                }
            }
            ptab[(size_t)d * 128 + tid] = acc;
        }
    }
}

// =============== kernel B: wave-per-target, barrier-free, grid 2048 ========================
// NO min-waves clamp (see kernel A note). Wave wid of block bid owns target t end-to-end;
// all LDS wave-private; no __syncthreads.
__global__ __launch_bounds__(256) void edge_agg_kernel(
    const void* __restrict__ trans, const int* __restrict__ srcArr,
    const float* __restrict__ hsrc, const float* __restrict__ htgt,
    const float* __restrict__ ptab, const float* __restrict__ V,
    const float* __restrict__ c_wrb, const float* __restrict__ c_av,
    const float* __restrict__ Wo, const float* __restrict__ Wg,
    const float* __restrict__ W2,
    const int* __restrict__ flag, void* __restrict__ outv)
{
    __shared__ __align__(16) float rbfS[4][K_][16];   // 7680 B
    __shared__ float lgS[4][K_ * 8];                  // 3840 B
    __shared__ float distS[4][32];                    //  512 B
    __shared__ float invS[4][8];                      //  128 B
    __shared__ float aggS[4][256];                    // 4096 B
    __shared__ float ybS[4][128];                     // 2048 B
    __shared__ float gbS[4][32];                      //  512 B

    const int bid = blockIdx.x, tid = threadIdx.x;
    const int lane = tid & 63, wid = tid >> 6;
    // XCD swizzle: block bid -> XCD bid&7 gets contiguous target range; wave owns one target
    const int t = ((bid & 7) << 10) | ((bid >> 3) << 2) | wid;
    const int bf = flag[0];

    // persistent per-wave operands (issue early; all L2-hot)
    const f2v* cw = (const f2v*)c_wrb;
    const f2v w0 = cw[0*64+lane],  w1 = cw[1*64+lane],  w2 = cw[2*64+lane],  w3 = cw[3*64+lane];
    const f2v w4 = cw[4*64+lane],  w5 = cw[5*64+lane],  w6 = cw[6*64+lane],  w7 = cw[7*64+lane];
    const f2v w8 = cw[8*64+lane],  w9 = cw[9*64+lane],  wA = cw[10*64+lane], wB = cw[11*64+lane];
    const f2v wC = cw[12*64+lane], wD = cw[13*64+lane], wE = cw[14*64+lane], wF = cw[15*64+lane];
    const f2v avv = ((const f2v*)c_av)[lane];
    const f2v ht  = *(const f2v*)(htgt + ((size_t)t << 7) + (lane << 1));

    // ---- phase 0: edge metadata in lane-slots (lane k<30 holds edge k) ----
    int srcv = 0, dv = 0;
    u64 vmask;
    {
        int src = 0;
        if (lane < K_) {
            src = srcArr[t * K_ + lane];
            src = (src < 0) ? 0 : ((src >= N_) ? (N_ - 1) : src);
        }
        float vx = ldf(trans, src*3+0, bf) - ldf(trans, t*3+0, bf);
        float vy = ldf(trans, src*3+1, bf) - ldf(trans, t*3+1, bf);
        float vz = ldf(trans, src*3+2, bf) - ldf(trans, t*3+2, bf);
        float dist = sqrtf(vx*vx + vy*vy + vz*vz);
        bool valid = isfinite(dist) && (dist > 1e-3f);
        vmask = __ballot(valid);
        srcv = src;
        int d = src - t + 512;
        dv = (d < 0) ? 0 : ((d > 1023) ? 1023 : d);
        if (lane < 32) distS[wid][lane] = dist;
    }

    // ---- rbf: 480 exps across the wave (e = k*16+j) ----
    #pragma unroll
    for (int it = 0; it < 8; ++it) {
        int e = lane + (it << 6);
        if (e < 480) {
            int k = e >> 4, j = e & 15;
            float dd = distS[wid][k];
            float tt = (dd - (float)j * (20.f/15.f)) * 0.8f;
            rbfS[wid][k][j] = __expf(-tt * tt);
        }
    }

    // ---- phase 1: 30 logits, whole wave per edge (lane = channel pair) ----
    #pragma unroll 2
    for (int k = 0; k < K_; ++k) {
        const int src = __builtin_amdgcn_readlane(srcv, k);
        const int d   = __builtin_amdgcn_readlane(dv, k);
        f2v hs = *(const f2v*)(hsrc + ((size_t)src << 7) + (lane << 1));
        f2v pt = *(const f2v*)(ptab + ((size_t)d << 7) + (lane << 1));
        f2v acc = (hs + ht) + pt;
        const float4* rp = (const float4*)(&rbfS[wid][k][0]);
        float4 ra = rp[0], rb = rp[1], rc = rp[2], rd = rp[3];   // broadcast reads
        f2v r0; r0.x = ra.x; r0.y = ra.y;
        f2v r1; r1.x = ra.z; r1.y = ra.w;
        f2v r2; r2.x = rb.x; r2.y = rb.y;
        f2v r3; r3.x = rb.z; r3.y = rb.w;
        f2v r4; r4.x = rc.x; r4.y = rc.y;
        f2v r5; r5.x = rc.z; r5.y = rc.w;
        f2v r6; r6.x = rd.x; r6.y = rd.y;
        f2v r7; r7.x = rd.z; r7.y = rd.w;
        PKFMA_LO(acc, r0, w0); PKFMA_HI(acc, r0, w1);
        PKFMA_LO(acc, r1, w2); PKFMA_HI(acc, r1, w3);
        PKFMA_LO(acc, r2, w4); PKFMA_HI(acc, r2, w5);
        PKFMA_LO(acc, r3, w6); PKFMA_HI(acc, r3, w7);
        PKFMA_LO(acc, r4, w8); PKFMA_HI(acc, r4, w9);
        PKFMA_LO(acc, r5, wA); PKFMA_HI(acc, r5, wB);
        PKFMA_LO(acc, r6, wC); PKFMA_HI(acc, r6, wD);
        PKFMA_LO(acc, r7, wE); PKFMA_HI(acc, r7, wF);
        float part = fsilu(acc.x) * avv.x + fsilu(acc.y) * avv.y;
        DPP_ADD8(part)
        float lg = (part >= 0.f) ? part : 0.2f * part;
        if (!((vmask >> k) & 1ull)) lg = -1e9f;
        lg = (fabsf(lg) < 1e30f) ? lg : -1e9f;
        if ((lane & 7) == 0) lgS[wid][k * 8 + (lane >> 3)] = lg;
    }

    // ---- phase 2: wave-local softmax (8 lanes, one per head) ----
    if (lane < 8) {
        float mx = -1e30f;
        #pragma unroll
        for (int k = 0; k < K_; ++k) mx = fmaxf(mx, lgS[wid][k * 8 + lane]);
        float den = 0.f;
        #pragma unroll
        for (int k = 0; k < K_; ++k) {
            float l = lgS[wid][k * 8 + lane];
            float e = (l > -1e8f) ? __expf(l - mx) : 0.f;
            lgS[wid][k * 8 + lane] = e; den += e;
        }
        invS[wid][lane] = 1.f / (den + 1e-9f);
    }

    // ---- phase 3: V aggregation (lane covers channels 2l,2l+1 and +128) ----
    {
        const int h = (lane & 31) >> 2;      // head of channel 2*lane (same for pair & +128)
        f2v a0; a0.x = 0.f; a0.y = 0.f;
        f2v a1; a1.x = 0.f; a1.y = 0.f;
        #pragma unroll
        for (int k = 0; k < K_; ++k) {
            const int src = __builtin_amdgcn_readlane(srcv, k);
            const float* vr = V + ((size_t)src << 8) + (lane << 1);
            f2v w = splat2(lgS[wid][k * 8 + h]);
            f2v x0 = *(const f2v*)(vr);
            f2v x1 = *(const f2v*)(vr + 128);
            a0 = __builtin_elementwise_fma(w, x0, a0);
            a1 = __builtin_elementwise_fma(w, x1, a1);
        }
        const float inv = invS[wid][h];
        a0.x *= inv; a0.y *= inv; a1.x *= inv; a1.y *= inv;
        *(f2v*)&aggS[wid][(lane << 1)]       = a0;
        *(f2v*)&aggS[wid][(lane << 1) + 128] = a1;
    }

    // ---- phase 4: epilogue, wave-local (2 passes of 64 lanes cover 128 outputs) ----
    #pragma unroll
    for (int p = 0; p < 2; ++p) {
        const int rr = (p << 1) | (lane >> 5);
        const int o  = lane & 31;
        float y = 0.f;
        #pragma unroll
        for (int c = 0; c < 64; ++c) y = fmaf(aggS[wid][rr * 64 + c], Wo[c * 32 + o], y);
        ybS[wid][rr * 32 + o] = y;
    }
    if (lane < 32) {
        float g = 0.f;
        #pragma unroll
        for (int o = 0; o < 32; ++o) g = fmaf(ybS[wid][o], Wg[o * 32 + lane], g);
        gbS[wid][lane] = fsilu(g);
    }
    #pragma unroll
    for (int p = 0; p < 2; ++p) {
        const int rr = (p << 1) | (lane >> 5);
        const int hh = lane & 31;
        float o = 0.f;
        #pragma unroll
        for (int g = 0; g < 32; ++g) o = fmaf(ybS[wid][rr * 32 + g] * gbS[wid][g], W2[g * 32 + hh], o);
        o = (fabsf(o) < 1e30f) ? o : 0.f;
        size_t idx = (size_t)t * 128 + (p << 6) + lane;
        if (bf) ((u16*)outv)[idx] = f2bf(o);
        else    ((float*)outv)[idx] = o;
    }
}

extern "C" void kernel_launch(void* const* d_in, const int* in_sizes, int n_in,
                              void* d_out, int out_size, void* d_ws, size_t ws_size,
                              hipStream_t stream)
{
    const void* rots         = d_in[0];
    const void* trans        = d_in[1];
    const void* node_emb     = d_in[2];
    /* d_in[3] = batch (unused; chains contiguous) */
    const void* x_mask       = d_in[4];
    const void* noising_mask = d_in[5];
    const void* Wa           = d_in[6];
    const void* avec         = d_in[7];
    const void* Wv           = d_in[8];
    const void* Wo           = d_in[9];
    const void* Wg           = d_in[10];
    const void* W2           = d_in[11];

    char* ws = (char*)d_ws;
    int*   flag    = (int*)  (ws + 0);            //        64
    int*   srcArr  = (int*)  (ws + 64);           //   983,040
    float* hsrc    = (float*)(ws + 983104);       // 4,194,304
    float* htgt    = (float*)(ws + 5177408);      // 4,194,304
    float* ptab    = (float*)(ws + 9371712);      //   524,288
    float* V       = (float*)(ws + 9896000);      // 8,388,608
    float* c_wrb   = (float*)(ws + 18284608);     //     8,192
    float* c_av    = (float*)(ws + 18292800);     //       512
    float* c_Wo    = (float*)(ws + 18293312);     //     8,192
    float* c_Wg    = (float*)(ws + 18301504);     //     4,096
    float* c_W2    = (float*)(ws + 18305600);     //     4,096  (end ~18.3 MB)

    hipLaunchKernelGGL(knn_prep_kernel, dim3(2048), dim3(256), 0, stream,
                       rots, trans, node_emb, x_mask, noising_mask,
                       Wa, avec, Wv, Wo, Wg, W2,
                       flag, srcArr, hsrc, htgt, ptab, V,
                       c_wrb, c_av, c_Wo, c_Wg, c_W2);
    hipLaunchKernelGGL(edge_agg_kernel, dim3(2048), dim3(256), 0, stream,
                       trans, srcArr, hsrc, htgt, ptab, V,
                       c_wrb, c_av, c_Wo, c_Wg, c_W2, flag, d_out);
}

// Round 5
// 202.148 us; speedup vs baseline: 2.5516x; 1.8184x over previous
//
#include <hip/hip_runtime.h>
#include <cstdint>

#define B_ 16
#define L_ 512
#define N_ 8192
#define K_ 30
#define E_ (N_*K_)
#define H_ 32
#define C_ 35

typedef uint16_t u16;
typedef uint32_t u32;
typedef unsigned long long u64;
typedef float f2v __attribute__((ext_vector_type(2)));

static __device__ __forceinline__ f2v splat2(float x) { f2v v; v.x = x; v.y = x; return v; }

// adaptive float load: bf16 (u16<<16) or fp32
static __device__ __forceinline__ float ldf(const void* p, int i, int bf) {
    return bf ? __uint_as_float(((u32)((const u16*)p)[i]) << 16)
              : ((const float*)p)[i];
}
static __device__ __forceinline__ float bfu16(u16 x) {
    return __uint_as_float(((u32)x) << 16);
}
// mask load: mode 0 = u8 bool, 1 = int32, 2 = int64 (little-endian low word)
static __device__ __forceinline__ int ldmask(const void* p, int i, int mode) {
    if (mode == 0) return ((const unsigned char*)p)[i] != 0;
    if (mode == 2) return ((const u32*)p)[2*i] != 0;
    return ((const u32*)p)[i] != 0;
}
// f32 -> bf16 RNE
static __device__ __forceinline__ u16 f2bf(float f) {
    u32 x = __float_as_uint(f);
    u32 r = x + 0x7FFFu + ((x >> 16) & 1u);
    return (u16)(r >> 16);
}
// fast silu (~1e-7 rel err; threshold 4.3e-3)
static __device__ __forceinline__ float fsilu(float x) {
    return x * __builtin_amdgcn_rcpf(1.f + __expf(-x));
}
// wave-uniform-index register broadcast (SGPR result -> free fmaf operand)
static __device__ __forceinline__ float RL(float x, int i) {
    return __uint_as_float((u32)__builtin_amdgcn_readlane((int)__float_as_uint(x), i));
}

// wave-level dtype detection (deterministic)
static __device__ __forceinline__ int detect_bf(const void* tr, int lane) {
    const u16* p = (const u16*)tr;
    int cnt = 0;
    for (int i = lane; i < 256; i += 64) {
        u16 v = p[2 * i];
        int e = (v >> 7) & 0xFF;
        if ((e >= 100 && e <= 141) || (v & 0x7FFFu) == 0) cnt++;
    }
    #pragma unroll
    for (int d = 1; d < 64; d <<= 1) cnt += __shfl_xor(cnt, d, 64);
    return cnt >= 192;
}
static __device__ __forceinline__ int detect_mm(const void* xmv, int lane) {
    const u32* xm = (const u32*)xmv;
    int anyBig = 0, oddNZ = 0;
    for (int i = lane; i < 1024; i += 64) {
        u32 w = xm[i];
        if (w & ~1u) anyBig = 1;
        if ((i & 1) && w) oddNZ = 1;
    }
    #pragma unroll
    for (int d = 1; d < 64; d <<= 1) {
        anyBig |= __shfl_xor(anyBig, d, 64);
        oddNZ  |= __shfl_xor(oddNZ, d, 64);
    }
    return anyBig ? 0 : (oddNZ ? 1 : 2);
}

__constant__ float cBB[9] = {-0.525f, 1.363f, 0.f,  0.f, 0.f, 0.f,  1.526f, 0.f, 0.f};

// u32 DPP min step (VALU pipe; d2>=0 -> f32 bit order == u32 order)
#define DPP_UMIN(var, CTRL) \
    { u32 o_ = (u32)__builtin_amdgcn_update_dpp((int)(var), (int)(var), CTRL, 0xF, 0xF, false); \
      (var) = (o_ < (var)) ? o_ : (var); }
#define DPP_UMIN_ALL(var) \
    DPP_UMIN(var, 0x111) DPP_UMIN(var, 0x112) DPP_UMIN(var, 0x114) \
    DPP_UMIN(var, 0x118) DPP_UMIN(var, 0x142) DPP_UMIN(var, 0x143)

// f32 add-reduce over 8-lane group via DPP (bit-identical to shfl_xor 1/2/4 tree)
#define DPP_ADD8(part) \
    part += __uint_as_float((u32)__builtin_amdgcn_update_dpp( \
        (int)__float_as_uint(part), (int)__float_as_uint(part), 0xB1, 0xF, 0xF, false)); \
    part += __uint_as_float((u32)__builtin_amdgcn_update_dpp( \
        (int)__float_as_uint(part), (int)__float_as_uint(part), 0x4E, 0xF, 0xF, false)); \
    part += __uint_as_float((u32)__builtin_amdgcn_update_dpp( \
        (int)__float_as_uint(part), (int)__float_as_uint(part), 0x141, 0xF, 0xF, false));

// packed f32 FMA with op_sel scalar broadcast from one half of rr.
// LO: both result halves use rr.low ; HI: both use rr.high.  fma per half ==
// scalar fmaf semantics -> bitwise identical to the unpacked form.
#define PKFMA_LO(acc, rr, w) \
    asm("v_pk_fma_f32 %0, %1, %2, %0 op_sel:[0,0,0] op_sel_hi:[0,1,1]" \
        : "+v"(acc) : "v"(rr), "v"(w))
#define PKFMA_HI(acc, rr, w) \
    asm("v_pk_fma_f32 %0, %1, %2, %0 op_sel:[1,0,0] op_sel_hi:[1,1,1]" \
        : "+v"(acc) : "v"(rr), "v"(w))

// =============== kernel 1: per-chain kNN (+ block 0 publishes dtype flags) =================
__global__ __launch_bounds__(256) void knn_kernel(const void* __restrict__ trans,
                                                  const void* __restrict__ xm,
                                                  int* __restrict__ flag,
                                                  int* __restrict__ srcArr)
{
    __shared__ float sX[L_], sY[L_], sZ[L_];
    __shared__ int flagS[1];
    const int bid = blockIdx.x, tid = threadIdx.x;
    const int lane = tid & 63, wid = tid >> 6;

    if (wid == 0) {
        int bf = detect_bf(trans, lane);
        if (bid == 0) {                     // publish flags for downstream kernels
            int mm = detect_mm(xm, lane);
            if (lane == 0) { flag[0] = bf; flag[1] = mm; }
        }
        if (lane == 0) flagS[0] = bf;
    }
    __syncthreads();
    const int bf = flagS[0];
    const int t0 = bid * 4;
    const int base = (t0 >> 9) << 9;
    if (bf) {
        const u16* tp = (const u16*)trans;
        for (int i = tid; i < L_; i += 256) {
            sX[i] = bfu16(tp[(base + i) * 3 + 0]);
            sY[i] = bfu16(tp[(base + i) * 3 + 1]);
            sZ[i] = bfu16(tp[(base + i) * 3 + 2]);
        }
    } else {
        const float* tp = (const float*)trans;
        for (int i = tid; i < L_; i += 256) {
            sX[i] = tp[(base + i) * 3 + 0];
            sY[i] = tp[(base + i) * 3 + 1];
            sZ[i] = tp[(base + i) * 3 + 2];
        }
    }
    __syncthreads();

    const int t = t0 + wid;
    const int l = t & 511;
    const float tx = sX[l], ty = sY[l], tz = sZ[l];

    u32 d2b[8];              // f32 bits of d2 (non-negative -> u32-order preserving)
    #pragma unroll
    for (int i = 0; i < 8; ++i) {
        int j = lane + (i << 6);
        // match numpy: ((dx*dx + dy*dy) + dz*dz), no FMA contraction
        float dx = __fsub_rn(tx, sX[j]);
        float dy = __fsub_rn(ty, sY[j]);
        float dz = __fsub_rn(tz, sZ[j]);
        float d2 = __fadd_rn(__fadd_rn(__fmul_rn(dx, dx), __fmul_rn(dy, dy)), __fmul_rn(dz, dz));
        if (j == l) d2 = __fadd_rn(d2, 1e9f);
        d2b[i] = __float_as_uint(d2);
    }

    int myres = 0;
    for (int k = 0; k < K_; ++k) {
        u32 bb = d2b[0]; int bs = 0;
        #pragma unroll
        for (int i = 1; i < 8; ++i)
            if (d2b[i] < bb) { bb = d2b[i]; bs = i; }
        u32 m = bb;
        DPP_UMIN_ALL(m)
        u32 gbits = (u32)__builtin_amdgcn_readlane((int)m, 63);
        u64 mask = __ballot(bb == gbits);
        u32 gidx;
        if (__popcll(mask) == 1) {
            int wl = __ffsll((long long)mask) - 1;
            gidx = (u32)__builtin_amdgcn_readlane((int)((bs << 6) | lane), wl);
        } else {
            u32 cand = (bb == gbits) ? (u32)((bs << 6) | lane) : 0xFFFFFFFFu;
            DPP_UMIN_ALL(cand)
            gidx = (u32)__builtin_amdgcn_readlane((int)cand, 63);
        }
        if (lane == (u32)k) myres = (int)(gidx & 511u);
        if ((gidx & 63u) == (u32)lane) {
            int ws = (int)(gidx >> 6);
            #pragma unroll
            for (int i = 0; i < 8; ++i)
                if (ws == i) d2b[i] = 0xFFFFFFFFu;
        }
    }
    if (lane < K_) srcArr[t * K_ + lane] = base + myres;
}

// =============== kernel 2: prep (node | ptab | conv) — barrier-free, LDS-free node ==========
__global__ __launch_bounds__(256) void prep_kernel(
    const void* __restrict__ rots, const void* __restrict__ node,
    const void* __restrict__ xm, const void* __restrict__ nm,
    const void* __restrict__ Wa, const void* __restrict__ av,
    const void* __restrict__ Wv, const void* __restrict__ Wo,
    const void* __restrict__ Wg, const void* __restrict__ W2,
    const int* __restrict__ flag,
    float* __restrict__ hsrc, float* __restrict__ htgt,
    float* __restrict__ ptab, float* __restrict__ V,
    float* __restrict__ c_wrb, float* __restrict__ c_av,
    float* __restrict__ c_Wo, float* __restrict__ c_Wg, float* __restrict__ c_W2)
{
    const int bid = blockIdx.x, tid = threadIdx.x;
    const int lane = tid & 63, wid = tid >> 6;
    const int bf = flag[0], mm = flag[1];

    if (bid < 2048) {
        // ---------------- node: wave wid owns node n ----------------
        const int n = bid * 4 + wid;

        float eA, eB, eC = 0.f;
        {
            int s = lane;                       // 0..63
            int r = s / 35, c = s - r * 35;
            if (c < H_)      eA = ldf(node, n * 128 + r * 32 + c, bf);
            else if (r == 0) eA = (c == 34) ? ((ldmask(nm, n, mm) && !ldmask(xm, n, mm)) ? 1.f : 0.f) : 0.f;
            else {
                int i = r - 1, a = c - 32;
                eA = ldf(rots, n*9 + i*3 + 0, bf) * cBB[a*3 + 0]
                   + ldf(rots, n*9 + i*3 + 1, bf) * cBB[a*3 + 1]
                   + ldf(rots, n*9 + i*3 + 2, bf) * cBB[a*3 + 2];
            }
            s = lane + 64;                      // 64..127
            r = s / 35; c = s - r * 35;
            if (c < H_)      eB = ldf(node, n * 128 + r * 32 + c, bf);
            else {
                int i = r - 1, a = c - 32;      // r>=1 always here
                eB = ldf(rots, n*9 + i*3 + 0, bf) * cBB[a*3 + 0]
                   + ldf(rots, n*9 + i*3 + 1, bf) * cBB[a*3 + 1]
                   + ldf(rots, n*9 + i*3 + 2, bf) * cBB[a*3 + 2];
            }
            if (lane < 12) {
                s = lane + 128;                 // 128..139
                r = s / 35; c = s - r * 35;
                if (c < H_)      eC = ldf(node, n * 128 + r * 32 + c, bf);
                else {
                    int i = r - 1, a = c - 32;
                    eC = ldf(rots, n*9 + i*3 + 0, bf) * cBB[a*3 + 0]
                       + ldf(rots, n*9 + i*3 + 1, bf) * cBB[a*3 + 1]
                       + ldf(rots, n*9 + i*3 + 2, bf) * cBB[a*3 + 2];
                }
            }
        }

        float a0 = 0.f, a1 = 0.f, b0 = 0.f, b1 = 0.f;
        float v0 = 0.f, v1 = 0.f, v2 = 0.f, v3 = 0.f;
        if (bf) {
            const u16* wa = (const u16*)Wa;
            const u16* wv = (const u16*)Wv;
            #pragma unroll
            for (int i = 0; i < 35; ++i) {
                float ei = RL(eA, i);
                a0 = fmaf(ei, bfu16(wa[i * 128 + lane]),        a0);
                a1 = fmaf(ei, bfu16(wa[i * 128 + lane + 64]),   a1);
                b0 = fmaf(ei, bfu16(wa[(35 + i) * 128 + lane]),      b0);
                b1 = fmaf(ei, bfu16(wa[(35 + i) * 128 + lane + 64]), b1);
            }
            #pragma unroll
            for (int cp = 0; cp < 35; ++cp) {
                float w = bfu16(wv[cp * 64 + lane]);
                float e1 = (35 + cp < 64) ? RL(eA, 35 + cp) : RL(eB, cp - 29);
                float e3 = (cp < 23) ? RL(eB, 41 + cp) : RL(eC, cp - 23);
                v0 = fmaf(RL(eA, cp), w, v0);
                v1 = fmaf(e1, w, v1);
                v2 = fmaf(RL(eB, cp + 6), w, v2);
                v3 = fmaf(e3, w, v3);
            }
        } else {
            const float* wa = (const float*)Wa;
            const float* wv = (const float*)Wv;
            #pragma unroll
            for (int i = 0; i < 35; ++i) {
                float ei = RL(eA, i);
                a0 = fmaf(ei, wa[i * 128 + lane],        a0);
                a1 = fmaf(ei, wa[i * 128 + lane + 64],   a1);
                b0 = fmaf(ei, wa[(35 + i) * 128 + lane],      b0);
                b1 = fmaf(ei, wa[(35 + i) * 128 + lane + 64], b1);
            }
            #pragma unroll
            for (int cp = 0; cp < 35; ++cp) {
                float w = wv[cp * 64 + lane];
                float e1 = (35 + cp < 64) ? RL(eA, 35 + cp) : RL(eB, cp - 29);
                float e3 = (cp < 23) ? RL(eB, 41 + cp) : RL(eC, cp - 23);
                v0 = fmaf(RL(eA, cp), w, v0);
                v1 = fmaf(e1, w, v1);
                v2 = fmaf(RL(eB, cp + 6), w, v2);
                v3 = fmaf(e3, w, v3);
            }
        }
        hsrc[(size_t)n * 128 + lane]      = a0;
        hsrc[(size_t)n * 128 + lane + 64] = a1;
        htgt[(size_t)n * 128 + lane]      = b0;
        htgt[(size_t)n * 128 + lane + 64] = b1;
        float* vp = V + (size_t)n * 256 + lane;
        vp[0] = v0; vp[64] = v1; vp[128] = v2; vp[192] = v3;

    } else if (bid < 2560) {
        // ---------------- ptab: 2 rows per block ----------------
        const int d   = (bid - 2048) * 2 + (tid >> 7);
        const int col = tid & 127;
        float dd = (float)(d - 512);
        float acc = 0.f;
        if (bf) {
            const u16* wa = (const u16*)Wa;
            #pragma unroll
            for (int q = 0; q < 8; ++q) {
                float fr = expf((float)(2 * q) * (-0.5756462732485115f)); // -ln(1e4)/16
                float ang = dd * fr;
                acc = fmaf(cosf(ang), bfu16(wa[(86 + q) * 128 + col]), acc);
                acc = fmaf(sinf(ang), bfu16(wa[(94 + q) * 128 + col]), acc);
            }
        } else {
            const float* wa = (const float*)Wa;
            #pragma unroll
            for (int q = 0; q < 8; ++q) {
                float fr = expf((float)(2 * q) * (-0.5756462732485115f));
                float ang = dd * fr;
                acc = fmaf(cosf(ang), wa[(86 + q) * 128 + col], acc);
                acc = fmaf(sinf(ang), wa[(94 + q) * 128 + col], acc);
            }
        }
        ptab[(size_t)d * 128 + col] = acc;

    } else {
        // ---------------- convert K3/K4 weights ----------------
        int g0 = (bid - 2560) * 256 + tid;
        for (int i = g0; i < 6272; i += 2048) {
            if      (i < 2048) c_wrb[i]        = ldf(Wa, 70 * 128 + i, bf);
            else if (i < 2176) c_av[i - 2048]  = ldf(av, i - 2048, bf);
            else if (i < 4224) c_Wo[i - 2176]  = ldf(Wo, i - 2176, bf);
            else if (i < 5248) c_Wg[i - 4224]  = ldf(Wg, i - 4224, bf);
            else               c_W2[i - 5248]  = ldf(W2, i - 5248, bf);
        }
    }
}

// =============== kernel 3: per-edge logits (E-parallel, 32 edges/wave, pk-f32 GEMV) ==========
// R5: per-edge indices go through readfirstlane (values are wave-uniform; bitwise no-op)
// so the 3 global loads/edge use SALU saddr addressing instead of 64-bit VGPR chains,
// and the 16 FMAs/edge are forced to v_pk_fma_f32 (bitwise == scalar fma per half).
__global__ __launch_bounds__(128) void logits_kernel(
    const void* __restrict__ trans, const int* __restrict__ srcArr,
    const float* __restrict__ hsrc, const float* __restrict__ htgt,
    const float* __restrict__ ptab,
    const float* __restrict__ c_wrb, const float* __restrict__ c_av,
    const int* __restrict__ flag, float* __restrict__ logitsw)
{
    __shared__ float rbfS[2][32][20];   // pad 20 -> float4 rows
    __shared__ int   srcS[2][32];
    __shared__ int   tgtS[2][32];
    __shared__ int   dS[2][32];         // d | (invalid << 16)
    __shared__ float lgS[2][256];       // staged logits for coalesced flush
    const int tid = threadIdx.x, wid = tid >> 6, lane = tid & 63;
    const int bf = flag[0];

    const f2v* cw = (const f2v*)c_wrb;
    const f2v w0 = cw[0*64+lane],  w1 = cw[1*64+lane],  w2 = cw[2*64+lane],  w3 = cw[3*64+lane];
    const f2v w4 = cw[4*64+lane],  w5 = cw[5*64+lane],  w6 = cw[6*64+lane],  w7 = cw[7*64+lane];
    const f2v w8 = cw[8*64+lane],  w9 = cw[9*64+lane],  wA = cw[10*64+lane], wB = cw[11*64+lane];
    const f2v wC = cw[12*64+lane], wD = cw[13*64+lane], wE = cw[14*64+lane], wF = cw[15*64+lane];
    const f2v avv = ((const f2v*)c_av)[lane];

    const int e0 = (blockIdx.x * 2 + wid) * 32;

    // ---- phase A: lane pairs share an edge; each computes 8 of 16 rbf exps ----
    {
        const int el  = lane & 31;
        const int e   = e0 + el;
        const int tgt = e / K_;
        int src = srcArr[e];
        src = (src < 0) ? 0 : ((src >= N_) ? (N_ - 1) : src);
        float vx = ldf(trans, src*3+0, bf) - ldf(trans, tgt*3+0, bf);
        float vy = ldf(trans, src*3+1, bf) - ldf(trans, tgt*3+1, bf);
        float vz = ldf(trans, src*3+2, bf) - ldf(trans, tgt*3+2, bf);
        float dist = sqrtf(vx*vx + vy*vy + vz*vz);
        bool valid = isfinite(dist) && (dist > 1e-3f);
        int d = src - tgt + 512;
        d = (d < 0) ? 0 : ((d > 1023) ? 1023 : d);
        if (lane < 32) {
            srcS[wid][el] = src;
            tgtS[wid][el] = tgt;
            dS[wid][el]   = d | (valid ? 0 : (1 << 16));
        }
        const int jb = (lane >> 5) * 8;
        #pragma unroll
        for (int j = 0; j < 8; ++j) {
            float tt = (dist - (float)(jb + j) * (20.f/15.f)) * 0.8f;
            rbfS[wid][el][jb + j] = __expf(-tt * tt);
        }
    }
    __syncthreads();

    // ---- phase B: wave sweeps its 32 edges (pk-f32, SGPR-based addressing) ----
    #pragma unroll 2
    for (int q = 0; q < 32; ++q) {
        const int src = __builtin_amdgcn_readfirstlane(srcS[wid][q]);
        const int tgt = __builtin_amdgcn_readfirstlane(tgtS[wid][q]);
        const int dm  = __builtin_amdgcn_readfirstlane(dS[wid][q]);
        const int d   = dm & 0xFFFF;
        const bool valid = (dm >> 16) == 0;

        f2v hs = *(const f2v*)(hsrc + ((size_t)src << 7) + (lane << 1));
        f2v ht = *(const f2v*)(htgt + ((size_t)tgt << 7) + (lane << 1));
        f2v pt = *(const f2v*)(ptab + ((size_t)d << 7) + (lane << 1));
        f2v acc = (hs + ht) + pt;
        const float4* rp = (const float4*)(&rbfS[wid][q][0]);
        float4 ra = rp[0], rb = rp[1], rc = rp[2], rd = rp[3];   // broadcast reads
        f2v r0; r0.x = ra.x; r0.y = ra.y;
        f2v r1; r1.x = ra.z; r1.y = ra.w;
        f2v r2; r2.x = rb.x; r2.y = rb.y;
        f2v r3; r3.x = rb.z; r3.y = rb.w;
        f2v r4; r4.x = rc.x; r4.y = rc.y;
        f2v r5; r5.x = rc.z; r5.y = rc.w;
        f2v r6; r6.x = rd.x; r6.y = rd.y;
        f2v r7; r7.x = rd.z; r7.y = rd.w;
        PKFMA_LO(acc, r0, w0); PKFMA_HI(acc, r0, w1);
        PKFMA_LO(acc, r1, w2); PKFMA_HI(acc, r1, w3);
        PKFMA_LO(acc, r2, w4); PKFMA_HI(acc, r2, w5);
        PKFMA_LO(acc, r3, w6); PKFMA_HI(acc, r3, w7);
        PKFMA_LO(acc, r4, w8); PKFMA_HI(acc, r4, w9);
        PKFMA_LO(acc, r5, wA); PKFMA_HI(acc, r5, wB);
        PKFMA_LO(acc, r6, wC); PKFMA_HI(acc, r6, wD);
        PKFMA_LO(acc, r7, wE); PKFMA_HI(acc, r7, wF);
        float part = fsilu(acc.x) * avv.x + fsilu(acc.y) * avv.y;
        DPP_ADD8(part)
        float lg = (part >= 0.f) ? part : 0.2f * part;
        if (!valid) lg = -1e9f;
        lg = (fabsf(lg) < 1e30f) ? lg : -1e9f;
        if ((lane & 7) == 0) lgS[wid][q * 8 + (lane >> 3)] = lg;
    }
    __syncthreads();
    {   // coalesced flush: 256 floats per wave = 1 float4 per lane
        float4* dst = (float4*)(logitsw + (size_t)e0 * 8);
        dst[lane] = ((const float4*)lgS[wid])[lane];
    }
}

// =============== kernel 4: softmax (dedup) + batched V sum + epilogue =====================
__global__ __launch_bounds__(256) void agg_out_kernel(
    const float* __restrict__ V, const int* __restrict__ srcArr,
    const float* __restrict__ logitsw,
    const float* __restrict__ Wo, const float* __restrict__ Wg,
    const float* __restrict__ W2,
    const int* __restrict__ flag, void* __restrict__ outv)
{
    __shared__ float lgS[240];          // logits -> unnormalized exp weights
    __shared__ float invS[8];
    __shared__ int   voffS[K_];
    __shared__ float aggS[256];
    __shared__ float ybuf[128];
    __shared__ float gbuf[32];
    const int bid = blockIdx.x, tid = threadIdx.x;
    const int t   = ((bid & 7) << 10) | (bid >> 3);   // XCD-locality swizzle
    const int bf = flag[0];

    if (tid < 240) lgS[tid] = logitsw[(size_t)t * 240 + tid];
    if (tid < K_) {
        int s = srcArr[t * K_ + tid];
        s = (s < 0) ? 0 : ((s >= N_) ? (N_ - 1) : s);
        voffS[tid] = s << 8;
    }
    __syncthreads();

    // softmax numerators once per (k,h): thread h handles head h
    if (tid < 8) {
        float mx = -1e30f;
        #pragma unroll
        for (int k = 0; k < K_; ++k) mx = fmaxf(mx, lgS[k * 8 + tid]);
        float den = 0.f;
        #pragma unroll
        for (int k = 0; k < K_; ++k) {
            float l = lgS[k * 8 + tid];
            float e = (l > -1e8f) ? __expf(l - mx) : 0.f;
            lgS[k * 8 + tid] = e; den += e;
        }
        invS[tid] = 1.f / (den + 1e-9f);
    }
    __syncthreads();

    // batched V gather (readfirstlane -> SALU saddr bases; 30 outstanding loads)
    {
        const int h = (tid & 63) >> 3;
        float vv[K_];
        #pragma unroll
        for (int k = 0; k < K_; ++k)
            vv[k] = V[__builtin_amdgcn_readfirstlane(voffS[k]) + tid];
        float acc = 0.f;
        #pragma unroll
        for (int k = 0; k < K_; ++k) acc = fmaf(lgS[k * 8 + h], vv[k], acc);
        aggS[tid] = acc * invS[h];
    }
    __syncthreads();

    // epilogue: y = agg @ W_o ; gate = silu(y0 @ W_g) ; out = (y*gate) @ W_2
    if (tid < 128) {
        int rr = tid >> 5, o = tid & 31;
        float y = 0.f;
        #pragma unroll
        for (int c = 0; c < 64; ++c) y = fmaf(aggS[rr * 64 + c], Wo[c * 32 + o], y);
        ybuf[tid] = y;
    }
    __syncthreads();
    if (tid < 32) {
        float g = 0.f;
        #pragma unroll
        for (int o = 0; o < 32; ++o) g = fmaf(ybuf[o], Wg[o * 32 + tid], g);
        gbuf[tid] = fsilu(g);
    }
    __syncthreads();
    if (tid < 128) {
        int rr = tid >> 5, hh = tid & 31;
        float o = 0.f;
        #pragma unroll
        for (int g = 0; g < 32; ++g) o = fmaf(ybuf[rr * 32 + g] * gbuf[g], W2[g * 32 + hh], o);
        o = (fabsf(o) < 1e30f) ? o : 0.f;
        size_t idx = (size_t)t * 128 + tid;
        if (bf) ((u16*)outv)[idx] = f2bf(o);
        else    ((float*)outv)[idx] = o;
    }
}

extern "C" void kernel_launch(void* const* d_in, const int* in_sizes, int n_in,
                              void* d_out, int out_size, void* d_ws, size_t ws_size,
                              hipStream_t stream)
{
    const void* rots         = d_in[0];
    const void* trans        = d_in[1];
    const void* node_emb     = d_in[2];
    /* d_in[3] = batch (unused; chains contiguous) */
    const void* x_mask       = d_in[4];
    const void* noising_mask = d_in[5];
    const void* Wa           = d_in[6];
    const void* avec         = d_in[7];
    const void* Wv           = d_in[8];
    const void* Wo           = d_in[9];
    const void* Wg           = d_in[10];
    const void* W2           = d_in[11];

    char* ws = (char*)d_ws;
    int*   flag    = (int*)  (ws + 0);            //        64
    int*   srcArr  = (int*)  (ws + 64);           //   983,040
    float* hsrc    = (float*)(ws + 983104);       // 4,194,304
    float* htgt    = (float*)(ws + 5177408);      // 4,194,304
    float* ptab    = (float*)(ws + 9371712);      //   524,288
    float* V       = (float*)(ws + 9896000);      // 8,388,608
    float* c_wrb   = (float*)(ws + 18284608);     //     8,192
    float* c_av    = (float*)(ws + 18292800);     //       512
    float* c_Wo    = (float*)(ws + 18293312);     //     8,192
    float* c_Wg    = (float*)(ws + 18301504);     //     4,096
    float* c_W2    = (float*)(ws + 18305600);     //     4,096
    float* logitsw = (float*)(ws + 18309696);     // 7,864,320  (end ~26.2 MB)

    hipLaunchKernelGGL(knn_kernel, dim3(N_/4), dim3(256), 0, stream,
                       trans, x_mask, flag, srcArr);
    hipLaunchKernelGGL(prep_kernel, dim3(2048 + 512 + 8), dim3(256), 0, stream,
                       rots, node_emb, x_mask, noising_mask,
                       Wa, avec, Wv, Wo, Wg, W2, flag,
                       hsrc, htgt, ptab, V,
                       c_wrb, c_av, c_Wo, c_Wg, c_W2);
    hipLaunchKernelGGL(logits_kernel, dim3(E_/64), dim3(128), 0, stream,
                       trans, srcArr, hsrc, htgt, ptab, c_wrb, c_av, flag, logitsw);
    hipLaunchKernelGGL(agg_out_kernel, dim3(N_), dim3(256), 0, stream,
                       V, srcArr, logitsw, c_Wo, c_Wg, c_W2, flag, d_out);
}